// Round 9
// baseline (366.380 us; speedup 1.0000x reference)
//
#include <hip/hip_runtime.h>
#include <hip/hip_bf16.h>
#include <math.h>

// ---------------------------------------------------------------------------
// TAPIR forward. State f32; cv + mixer GEMMs + hid3 conv via bf16 MFMA.
// fg[64,64,256] hg[128,128,128] qf[1024,256] hq[1024,128] -> out[1024,4]
// ---------------------------------------------------------------------------

#define NQ 1024
#define TEMPF 20.0f
#define DIMV 388
#define INDIM 535
#define KPAD 544
#define HID 512

// workspace layout (float offsets)
#define WS_CV      0                          // 1024*4096 (dead after stripe)
#define WS_FGAVG   (WS_CV + NQ*4096)          // 32*32*256
#define WS_POS     (WS_FGAVG + 262144)        // 1024*2
#define WS_OCC     (WS_POS + NQ*2)            // 1024
#define WS_EXPD    (WS_OCC + NQ)              // 1024
#define WS_FEATS   (WS_EXPD + NQ)             // 1024*384
#define WS_MLPIN   (WS_FEATS + NQ*384)        // bf16 mlp_in [1024][544] (278528 fl)
#define WS_HIDDEN  (WS_MLPIN + NQ*KPAD)       // SUM3 f32 overlay region
#define WS_W3B     (WS_HIDDEN + NQ*HID)       // bf16 hid3 B-fragments (5120 bf16)
// overlays:
#define WS_PART    (WS_MLPIN + 278528)        // 1024*32*4 softmax partials
#define WS_SUM3    WS_HIDDEN                  // 1024*16*32 hid3 relu-sums (dead after merge)
#define WS_WIT     WS_CV                      // bf16 [512][544] mix_in_w^T
#define WS_WOT     (WS_CV + 139264)           // bf16 [448][512] mix_out_w^T

#define OP 72                                 // occ LDS x-pitch
#define CVP 68                                // cvs LDS pitch
#define HPITCH 520                            // hidden LDS pitch (bank-decorrelated)

typedef __attribute__((ext_vector_type(8))) short bf16x8;
typedef __attribute__((ext_vector_type(4))) float f32x4;

union U4B8 { uint4 u; bf16x8 v; };

// ---------------------------------------------------------------------------
// prep: fg 2x2 avg pyramid, feats=concat(hq,qf), W3B fragment pack, zero SUM3
// ---------------------------------------------------------------------------
__global__ __launch_bounds__(256) void k_prep(
    const float* __restrict__ fg, const float* __restrict__ qf,
    const float* __restrict__ hq, const float* __restrict__ w3,
    float* __restrict__ ws) {
  int i = blockIdx.x * 256 + threadIdx.x;
  if (i < 262144) {
    int c = i & 255, ox = (i >> 8) & 31, oy = i >> 13;
    const float* b = fg + (((oy * 2) * 64 + ox * 2) << 8) + c;
    ws[WS_FGAVG + i] = 0.25f * (b[0] + b[256] + b[16384] + b[16384 + 256]);
  } else if (i < 262144 + 393216) {
    int j = i - 262144;
    int n = j / 384, c = j - n * 384;
    ws[WS_FEATS + j] = (c < 128) ? hq[n * 128 + c] : qf[n * 256 + c - 128];
  } else if (i < 262144 + 393216 + 5120) {
    int j = i - (262144 + 393216);
    int e = j & 7, qd = (j >> 3) & 3, nl = (j >> 5) & 15;
    int nt = (j >> 9) & 1, kt = j >> 10;
    int k = kt * 32 + qd * 8 + e;
    int ic = k & 15, tap = k >> 4;
    int oc = nt * 16 + nl;
    float v = (tap < 9) ? w3[(oc * 16 + ic) * 9 + tap] : 0.f;
    ((__hip_bfloat16*)(ws + WS_W3B))[j] = __float2bfloat16(v);
  } else if (i < 262144 + 393216 + 5120 + 524288) {
    int j = i - (262144 + 393216 + 5120);
    ws[WS_SUM3 + j] = 0.f;
  }
}

// ---------------------------------------------------------------------------
// cost volume (bf16 MFMA): cv[m=query][n=pixel] = qf . fg, K=256.
// ---------------------------------------------------------------------------
__global__ __launch_bounds__(256) void k_cv(
    const float* __restrict__ qf, const float* __restrict__ fg,
    float* __restrict__ ws) {
  __shared__ __hip_bfloat16 A_s[32 * 32];
  __shared__ __hip_bfloat16 B_s[64 * 32];
  const int t = threadIdx.x;
  const int wv = t >> 6, lane = t & 63;
  const int wm = wv & 1, wn = wv >> 1;
  const int quad = lane >> 4, nl = lane & 15;
  const int p0 = blockIdx.x * 64, m0 = blockIdx.y * 32;
  f32x4 acc0 = {0.f, 0.f, 0.f, 0.f};
  f32x4 acc1 = {0.f, 0.f, 0.f, 0.f};

  for (int k0 = 0; k0 < 256; k0 += 32) {
    {
      int r = t >> 3, c = t & 7;
      float4 v = *(const float4*)&qf[(m0 + r) * 256 + k0 + c * 4];
      union { __hip_bfloat16 h[4]; uint2 u; } pk;
      pk.h[0] = __float2bfloat16(v.x); pk.h[1] = __float2bfloat16(v.y);
      pk.h[2] = __float2bfloat16(v.z); pk.h[3] = __float2bfloat16(v.w);
      *(uint2*)&A_s[r * 32 + c * 4] = pk.u;
    }
    {
      int r = t >> 2, c = t & 3;
      const float* src = &fg[(p0 + r) * 256 + k0 + c * 8];
      float4 v0 = *(const float4*)src;
      float4 v1 = *(const float4*)(src + 4);
      union { __hip_bfloat16 h[8]; uint4 u; } pk;
      pk.h[0] = __float2bfloat16(v0.x); pk.h[1] = __float2bfloat16(v0.y);
      pk.h[2] = __float2bfloat16(v0.z); pk.h[3] = __float2bfloat16(v0.w);
      pk.h[4] = __float2bfloat16(v1.x); pk.h[5] = __float2bfloat16(v1.y);
      pk.h[6] = __float2bfloat16(v1.z); pk.h[7] = __float2bfloat16(v1.w);
      *(uint4*)&B_s[r * 32 + c * 8] = pk.u;
    }
    __syncthreads();
    bf16x8 a = *(const bf16x8*)&A_s[(16 * wm + nl) * 32 + quad * 8];
    bf16x8 b0 = *(const bf16x8*)&B_s[(32 * wn + nl) * 32 + quad * 8];
    bf16x8 b1 = *(const bf16x8*)&B_s[(32 * wn + 16 + nl) * 32 + quad * 8];
    acc0 = __builtin_amdgcn_mfma_f32_16x16x32_bf16(a, b0, acc0, 0, 0, 0);
    acc1 = __builtin_amdgcn_mfma_f32_16x16x32_bf16(a, b1, acc1, 0, 0, 0);
    __syncthreads();
  }
#pragma unroll
  for (int nt = 0; nt < 2; nt++) {
    int n = p0 + 32 * wn + nt * 16 + nl;
#pragma unroll
    for (int r = 0; r < 4; r++) {
      int m = m0 + 16 * wm + quad * 4 + r;
      ws[WS_CV + m * 4096 + n] = (nt ? acc1[r] : acc0[r]);
    }
  }
}

// ---------------------------------------------------------------------------
// head stripe kernel: 1 block = (query, 4-row stripe). 16384 blocks.
// ---------------------------------------------------------------------------
__global__ __launch_bounds__(256, 4) void k_head_stripe(
    const float* __restrict__ h1w, const float* __restrict__ h1b,
    const float* __restrict__ h2w, const float* __restrict__ h2b,
    const float* __restrict__ h3b, float* __restrict__ ws) {
  __shared__ float cvs[8 * CVP];         // cv rows y0-2..y0+5, x -1..64
  __shared__ float occ[6 * 16 * OP];     // [r][ch][x+4]

  const int bx = blockIdx.x;
  const int q = bx >> 4, st = bx & 15;
  const int y0 = st * 4;
  const int t = threadIdx.x;
  const int wv = t >> 6, lane = t & 63;
  const int role = (wv + bx) & 3;
  const float* cv = ws + WS_CV + q * 4096;

  // halo cols 0-3 / 68-71 of all 96 (r,ch) rows
  if (t < 192) {
    int rc = t >> 1, side = t & 1;
    *(float4*)&occ[rc * OP + side * 68] = make_float4(0.f, 0.f, 0.f, 0.f);
  }
  // out-of-range occ row (st==0: r=0 ; st==15: r=5)
  if (st == 0 || st == 15) {
    int r = (st == 0) ? 0 : 5;
    for (int i = t; i < 16 * 18; i += 256)
      *(float4*)&occ[(r * 16 + (i / 18)) * OP + (i % 18) * 4] =
          make_float4(0.f, 0.f, 0.f, 0.f);
  }
  // cv stripe load
#pragma unroll
  for (int j = 0; j < 2; j++) {
    int i = t + 256 * j;
    int lr = i >> 6, x = i & 63;
    int g = y0 - 2 + lr;
    cvs[lr * CVP + x + 1] = (g >= 0 && g < 64) ? cv[g * 64 + x] : 0.f;
  }
  if (t < 32) {
    int rr = t >> 2, c = t & 3;
    cvs[rr * CVP + ((c == 0) ? 0 : (64 + c))] = 0.f;  // idx 0,65,66,67
  }
  __syncthreads();

  // ---- P1: hid1 conv, 1 px/lane, wave = 4 channels (balanced) ----
  {
    const int x = lane;
    const int chg = wv * 4;
    float w1r[4][9], b1r[4];
#pragma unroll
    for (int k = 0; k < 4; k++) {
      b1r[k] = h1b[chg + k];
#pragma unroll
      for (int j = 0; j < 9; j++) w1r[k][j] = h1w[(chg + k) * 9 + j];
    }
    for (int r = 0; r < 6; r++) {
      int yo = y0 - 1 + r;
      if (yo >= 0 && yo <= 63) {
        float p[9];
#pragma unroll
        for (int ky = 0; ky < 3; ky++) {
          const float* cp = &cvs[(r + ky) * CVP + x];
          p[3 * ky] = cp[0]; p[3 * ky + 1] = cp[1]; p[3 * ky + 2] = cp[2];
        }
#pragma unroll
        for (int k = 0; k < 4; k++) {
          float a = b1r[k];
#pragma unroll
          for (int j = 0; j < 9; j++) a += w1r[k][j] * p[j];
          occ[(r * 16 + chg + k) * OP + x + 4] = fmaxf(a, 0.f);
        }
      }
    }
  }
  __syncthreads();

  if (role == 1 || role == 2) {
    // ---- hid3 MFMA: one output row (oyl = role-1). M=32 ox, N=32 oc, K=160.
    const __hip_bfloat16* W3B = (const __hip_bfloat16*)(ws + WS_W3B);
    const int oyl = role - 1;
    const int nl = lane & 15;
    const int qd = lane >> 4, qh = qd >> 1, ql = qd & 1;
    f32x4 acc00 = {0.f,0.f,0.f,0.f}, acc01 = {0.f,0.f,0.f,0.f};
    f32x4 acc10 = {0.f,0.f,0.f,0.f}, acc11 = {0.f,0.f,0.f,0.f};
#pragma unroll
    for (int kt = 0; kt < 5; kt++) {
      int tap = kt * 2 + qh;               // 0..9 (9 => zero pad)
      int tv = (tap < 9) ? tap : 0;
      int ky = (tv >= 6) ? 2 : ((tv >= 3) ? 1 : 0);
      int kx = tv - 3 * ky;
      const float* ap =
          &occ[((2 * oyl + 1 + ky) * 16 + ql * 8) * OP + 4 + kx + 2 * nl];
      union { bf16x8 v; __hip_bfloat16 h[8]; } a0u, a1u;
      if (tap < 9) {
#pragma unroll
        for (int j = 0; j < 8; j++) {
          a0u.h[j] = __float2bfloat16(ap[j * OP]);
          a1u.h[j] = __float2bfloat16(ap[j * OP + 32]);
        }
      } else {
#pragma unroll
        for (int j = 0; j < 8; j++) {
          a0u.h[j] = __float2bfloat16(0.f);
          a1u.h[j] = __float2bfloat16(0.f);
        }
      }
      bf16x8 b0 = *(const bf16x8*)&W3B[((kt * 2 + 0) * 16 + nl) * 32 + qd * 8];
      bf16x8 b1 = *(const bf16x8*)&W3B[((kt * 2 + 1) * 16 + nl) * 32 + qd * 8];
      acc00 = __builtin_amdgcn_mfma_f32_16x16x32_bf16(a0u.v, b0, acc00, 0, 0, 0);
      acc01 = __builtin_amdgcn_mfma_f32_16x16x32_bf16(a0u.v, b1, acc01, 0, 0, 0);
      acc10 = __builtin_amdgcn_mfma_f32_16x16x32_bf16(a1u.v, b0, acc10, 0, 0, 0);
      acc11 = __builtin_amdgcn_mfma_f32_16x16x32_bf16(a1u.v, b1, acc11, 0, 0, 0);
    }
    float bb0 = h3b[nl], bb1 = h3b[16 + nl];
    float s0 = 0.f, s1 = 0.f;
#pragma unroll
    for (int r = 0; r < 4; r++) {
      s0 += fmaxf(acc00[r] + bb0, 0.f) + fmaxf(acc10[r] + bb0, 0.f);
      s1 += fmaxf(acc01[r] + bb1, 0.f) + fmaxf(acc11[r] + bb1, 0.f);
    }
    s0 += __shfl_xor(s0, 16); s0 += __shfl_xor(s0, 32);
    s1 += __shfl_xor(s1, 16); s1 += __shfl_xor(s1, 32);
    if (lane < 16) {
      atomicAdd(&ws[WS_SUM3 + (q * 16 + st) * 32 + nl], s0);
      atomicAdd(&ws[WS_SUM3 + (q * 16 + st) * 32 + 16 + nl], s1);
    }
  } else {
    // ---- hid2 + softmax partial on 2 rows ----
    const int rl = ((role == 3) ? 2 : 0) + (lane >> 5);
    const int yg = y0 + rl;
    const int x0 = (lane & 31) * 2;
    float pa = 0.f, pb = 0.f;
    for (int ch = 0; ch < 16; ch++) {
#pragma unroll
      for (int ky = 0; ky < 3; ky++) {
        const float* bp = &occ[((rl + ky) * 16 + ch) * OP + x0];
        float f0 = bp[3];
        float2 fm = *(const float2*)(bp + 4);
        float f3 = bp[6];
        float wa = h2w[ch * 9 + 3 * ky], wb = h2w[ch * 9 + 3 * ky + 1],
              wc = h2w[ch * 9 + 3 * ky + 2];
        pa += wa * f0 + wb * fm.x + wc * fm.y;
        pb += wa * fm.x + wb * fm.y + wc * f3;
      }
    }
    float bb = h2b[0];
    float v0 = (pa + bb) * TEMPF, v1 = (pb + bb) * TEMPF;
    float mg = fmaxf(v0, v1);
#pragma unroll
    for (int off = 1; off < 64; off <<= 1) mg = fmaxf(mg, __shfl_xor(mg, off));
    float e0 = __expf(v0 - mg), e1 = __expf(v1 - mg);
    float s = e0 + e1;
    float sx = e0 * (float)x0 + e1 * (float)(x0 + 1);
    float sy = s * (float)yg;
#pragma unroll
    for (int off = 1; off < 64; off <<= 1) {
      s += __shfl_xor(s, off);
      sx += __shfl_xor(sx, off);
      sy += __shfl_xor(sy, off);
    }
    if (lane == 0) {
      int slot = q * 32 + st * 2 + ((role == 3) ? 1 : 0);
      *(float4*)&ws[WS_PART + slot * 4] = make_float4(mg, s, sx, sy);
    }
  }
}

// ---------------------------------------------------------------------------
// head merge (blocks 0-255) + mixer weight convert (all 1984 blocks)
// ---------------------------------------------------------------------------
__global__ __launch_bounds__(256) void k_merge_cvt(
    const float* __restrict__ w4, const float* __restrict__ b4,
    const float* __restrict__ w5, const float* __restrict__ b5,
    const float* __restrict__ wi, const float* __restrict__ wo,
    float* __restrict__ ws) {
  {
    int i = blockIdx.x * 256 + threadIdx.x;
    __hip_bfloat16* WIT = (__hip_bfloat16*)(ws + WS_WIT);
    __hip_bfloat16* WOT = (__hip_bfloat16*)(ws + WS_WOT);
    if (i < 278528) {
      int n = i / KPAD, k = i - n * KPAD;
      float v = (k < INDIM) ? wi[k * HID + n] : 0.f;
      WIT[i] = __float2bfloat16(v);
    } else if (i < 278528 + 229376) {
      int j = i - 278528;
      int n = j >> 9, k = j & 511;
      float v = (n < DIMV) ? wo[k * DIMV + n] : 0.f;
      WOT[j] = __float2bfloat16(v);
    }
  }
  if (blockIdx.x >= 256) return;

  __shared__ float sums_s[4][32];
  __shared__ float o4s[4][16];
  int t = threadIdx.x, wv = t >> 6, lane = t & 63;
  int q = blockIdx.x * 4 + wv;

  float M = -1e30f, S = 0.f, SX = 0.f, SY = 0.f;
  if (lane < 32) {
    float4 pv = *(const float4*)&ws[WS_PART + (q * 32 + lane) * 4];
    M = pv.x; S = pv.y; SX = pv.z; SY = pv.w;
  }
#pragma unroll
  for (int off = 1; off < 64; off <<= 1) {
    float Mo = __shfl_xor(M, off), So = __shfl_xor(S, off);
    float SXo = __shfl_xor(SX, off), SYo = __shfl_xor(SY, off);
    float Mn = fmaxf(M, Mo);
    float c1 = __expf(M - Mn), c2 = __expf(Mo - Mn);
    S = S * c1 + So * c2; SX = SX * c1 + SXo * c2; SY = SY * c1 + SYo * c2;
    M = Mn;
  }
  if (lane == 0) {
    ws[WS_POS + q * 2 + 0] = (SX / S) * 8.0f;
    ws[WS_POS + q * 2 + 1] = (SY / S) * 8.0f;
  }

  int ch = lane & 31, half = lane >> 5;
  float sm = 0.f;
#pragma unroll
  for (int s8 = 0; s8 < 8; s8++)
    sm += ws[WS_SUM3 + (q * 16 + half * 8 + s8) * 32 + ch];
  sm += __shfl_xor(sm, 32);
  if (lane < 32) sums_s[wv][lane] = sm * (1.f / 1024.f);
  __syncthreads();
  if (lane < 16) {
    float a = b4[lane];
#pragma unroll
    for (int i = 0; i < 32; i++) a += sums_s[wv][i] * w4[i * 16 + lane];
    o4s[wv][lane] = fmaxf(a, 0.f);
  }
  __syncthreads();
  if (lane < 2) {
    float r = b5[lane];
#pragma unroll
    for (int j = 0; j < 16; j++) r += o4s[wv][j] * w5[j * 2 + lane];
    if (lane == 0) ws[WS_OCC + q] = r;
    else           ws[WS_EXPD + q] = r;
  }
}

// ---------------------------------------------------------------------------
// correlation + bf16 mlp_in assembly. 1 block = 1 query.
// ---------------------------------------------------------------------------
__global__ __launch_bounds__(256) void k_corr(
    const float* __restrict__ fg, const float* __restrict__ hg,
    float* __restrict__ ws) {
  __shared__ float qs[384];
  __shared__ float dbuf[3][64];
  int t = threadIdx.x;
  int wv = t >> 6, lane = t & 63;
  int cl = lane & 15, sub = lane >> 4;
  int n = blockIdx.x;
  const float* feats = ws + WS_FEATS + n * 384;
  float posx = ws[WS_POS + n * 2 + 0];
  float posy = ws[WS_POS + n * 2 + 1];
  __hip_bfloat16* mi = (__hip_bfloat16*)(ws + WS_MLPIN) + n * KPAD;

  for (int col = t; col < 384; col += 256) {
    float v = feats[col];
    qs[col] = v;
    mi[4 + col] = __float2bfloat16(v);
  }
  if (t < 4) {
    float v = (t == 2) ? ws[WS_OCC + n] : ((t == 3) ? ws[WS_EXPD + n] : 0.f);
    mi[t] = __float2bfloat16(v);
  }
  __syncthreads();

  float4 qh0 = *(const float4*)&qs[cl * 4];
  float4 qh1 = *(const float4*)&qs[64 + cl * 4];
  float4 qq0 = *(const float4*)&qs[128 + cl * 4];
  float4 qq1 = *(const float4*)&qs[192 + cl * 4];
  float4 qq2 = *(const float4*)&qs[256 + cl * 4];
  float4 qq3 = *(const float4*)&qs[320 + cl * 4];

#pragma unroll
  for (int L = 0; L < 3; L++) {
    const float* grid;
    int Hg, Wg;
    float scl;
    if (L == 0)      { grid = hg;             Hg = 128; Wg = 128; scl = 0.25f; }
    else if (L == 1) { grid = fg;             Hg = 64;  Wg = 64;  scl = 0.125f; }
    else             { grid = ws + WS_FGAVG;  Hg = 32;  Wg = 32;  scl = 0.0625f; }
    float cy = posy * scl, cx = posx * scl;
    int iy = (int)floorf(cy), ix = (int)floorf(cx);
#pragma unroll
    for (int g = 0; g < 4; g++) {
      int p = wv * 16 + g * 4 + sub;
      int a = p >> 3, b = p & 7;
      int row = iy + a - 3; row = row < 0 ? 0 : (row > Hg - 1 ? Hg - 1 : row);
      int col = ix + b - 3; col = col < 0 ? 0 : (col > Wg - 1 ? Wg - 1 : col);
      float acc;
      if (L == 0) {
        const float* gp = grid + (row * Wg + col) * 128 + cl * 4;
        float4 g0 = *(const float4*)gp;
        float4 g1 = *(const float4*)(gp + 64);
        acc = g0.x * qh0.x + g0.y * qh0.y + g0.z * qh0.z + g0.w * qh0.w +
              g1.x * qh1.x + g1.y * qh1.y + g1.z * qh1.z + g1.w * qh1.w;
      } else {
        const float* gp = grid + (row * Wg + col) * 256 + cl * 4;
        float4 g0 = *(const float4*)gp;
        float4 g1 = *(const float4*)(gp + 64);
        float4 g2 = *(const float4*)(gp + 128);
        float4 g3 = *(const float4*)(gp + 192);
        acc = g0.x * qq0.x + g0.y * qq0.y + g0.z * qq0.z + g0.w * qq0.w +
              g1.x * qq1.x + g1.y * qq1.y + g1.z * qq1.z + g1.w * qq1.w +
              g2.x * qq2.x + g2.y * qq2.y + g2.z * qq2.z + g2.w * qq2.w +
              g3.x * qq3.x + g3.y * qq3.y + g3.z * qq3.z + g3.w * qq3.w;
      }
      acc += __shfl_xor(acc, 1);
      acc += __shfl_xor(acc, 2);
      acc += __shfl_xor(acc, 4);
      acc += __shfl_xor(acc, 8);
      if (cl == 0) dbuf[L][p] = acc;
    }
  }
  __syncthreads();

  if (t < 147) {
    int L = t / 49, s = t - L * 49;
    int sa = s / 7, sb = s - sa * 7;
    float scl = (L == 0) ? 0.25f : ((L == 1) ? 0.125f : 0.0625f);
    float cy = posy * scl, cx = posx * scl;
    float wy = cy - floorf(cy), wx = cx - floorf(cx);
    int i00 = sa * 8 + sb;
    float d00 = dbuf[L][i00], d01 = dbuf[L][i00 + 1];
    float d10 = dbuf[L][i00 + 8], d11 = dbuf[L][i00 + 9];
    float corr = (1.f - wy) * (1.f - wx) * d00 + (1.f - wy) * wx * d01 +
                 wy * (1.f - wx) * d10 + wy * wx * d11;
    mi[388 + t] = __float2bfloat16(corr);
  }
}

// ---------------------------------------------------------------------------
__device__ __forceinline__ float gelu_tanh(float x) {
  float z = 0.7978845608028654f * (x + 0.044715f * x * x * x);
  z = fminf(fmaxf(z, -15.f), 15.f);
  float e = __expf(2.f * z);
  float th = (e - 1.f) / (e + 1.f);
  return 0.5f * x * (1.f + th);
}

// ---------------------------------------------------------------------------
// fused mixer (MFMA bf16, barrier-free K-loops, direct-global fragments):
// block = 16 query rows. Phase A: hidden=gelu(mlp_in@WIT^T+bi) -> LDS.
// Phase B: res = hidden@WOT^T+bo -> state update + out.
// ---------------------------------------------------------------------------
__global__ __launch_bounds__(256) void k_mix(
    const float* __restrict__ bi, const float* __restrict__ bo,
    float* __restrict__ ws, float* __restrict__ out) {
  __shared__ __hip_bfloat16 Hs[16 * HPITCH];
  const int t = threadIdx.x;
  const int wv = t >> 6, lane = t & 63;
  const int quad = lane >> 4, nl = lane & 15;
  const int m0 = blockIdx.x * 16;
  const unsigned short* MI = (const unsigned short*)(ws + WS_MLPIN);
  const unsigned short* WIT = (const unsigned short*)(ws + WS_WIT);
  const unsigned short* WOT = (const unsigned short*)(ws + WS_WOT);

  // ---- phase A: cols wv*128 .. +127 (8 n-tiles) ----
  {
    f32x4 acc[8];
#pragma unroll
    for (int i = 0; i < 8; i++) acc[i] = (f32x4){0.f, 0.f, 0.f, 0.f};
    const unsigned short* Ap = &MI[(m0 + nl) * KPAD + quad * 8];
    const unsigned short* Bp = &WIT[(wv * 128 + nl) * KPAD + quad * 8];
    U4B8 a_c, b_c[8], a_n, b_n[8];
    a_c.u = *(const uint4*)Ap;
#pragma unroll
    for (int i = 0; i < 8; i++) b_c[i].u = *(const uint4*)(Bp + i * 16 * KPAD);
    for (int k0 = 0; k0 < KPAD; k0 += 32) {
      if (k0 + 32 < KPAD) {
        a_n.u = *(const uint4*)(Ap + k0 + 32);
#pragma unroll
        for (int i = 0; i < 8; i++)
          b_n[i].u = *(const uint4*)(Bp + i * 16 * KPAD + k0 + 32);
      }
#pragma unroll
      for (int i = 0; i < 8; i++)
        acc[i] = __builtin_amdgcn_mfma_f32_16x16x32_bf16(a_c.v, b_c[i].v,
                                                         acc[i], 0, 0, 0);
      a_c = a_n;
#pragma unroll
      for (int i = 0; i < 8; i++) b_c[i] = b_n[i];
    }
#pragma unroll
    for (int i = 0; i < 8; i++) {
      int col = wv * 128 + i * 16 + nl;
      float bv = bi[col];
#pragma unroll
      for (int r = 0; r < 4; r++) {
        int row = quad * 4 + r;
        Hs[row * HPITCH + col] = __float2bfloat16(gelu_tanh(acc[i][r] + bv));
      }
    }
  }
  __syncthreads();

  // ---- phase B: cols wv*112 .. +111 (7 n-tiles), K=512 from LDS hidden ----
  {
    f32x4 acc[7];
#pragma unroll
    for (int i = 0; i < 7; i++) acc[i] = (f32x4){0.f, 0.f, 0.f, 0.f};
    const unsigned short* Bp = &WOT[(wv * 112 + nl) * HID + quad * 8];
    U4B8 b_c[7], b_n[7];
#pragma unroll
    for (int i = 0; i < 7; i++) b_c[i].u = *(const uint4*)(Bp + i * 16 * HID);
    for (int k0 = 0; k0 < HID; k0 += 32) {
      if (k0 + 32 < HID) {
#pragma unroll
        for (int i = 0; i < 7; i++)
          b_n[i].u = *(const uint4*)(Bp + i * 16 * HID + k0 + 32);
      }
      bf16x8 a = *(const bf16x8*)&Hs[nl * HPITCH + k0 + quad * 8];
#pragma unroll
      for (int i = 0; i < 7; i++)
        acc[i] = __builtin_amdgcn_mfma_f32_16x16x32_bf16(a, b_c[i].v,
                                                         acc[i], 0, 0, 0);
#pragma unroll
      for (int i = 0; i < 7; i++) b_c[i] = b_n[i];
    }
#pragma unroll
    for (int i = 0; i < 7; i++) {
      int col = wv * 112 + i * 16 + nl;
      if (col >= DIMV) continue;
      float bv = bo[col];
#pragma unroll
      for (int r = 0; r < 4; r++) {
        int m = m0 + quad * 4 + r;
        float rr = acc[i][r] + bv;
        if (col < 2) {
          float v = ws[WS_POS + m * 2 + col] + rr;
          ws[WS_POS + m * 2 + col] = v;
          out[m * 4 + col] = v;
        } else if (col == 2) {
          float v = ws[WS_OCC + m] + rr;
          ws[WS_OCC + m] = v;
          out[m * 4 + 2] = v;
        } else if (col == 3) {
          float v = ws[WS_EXPD + m] + rr;
          ws[WS_EXPD + m] = v;
          out[m * 4 + 3] = v;
        } else {
          ws[WS_FEATS + m * 384 + (col - 4)] += rr;
        }
      }
    }
  }
}

// ---------------------------------------------------------------------------
extern "C" void kernel_launch(void* const* d_in, const int* in_sizes, int n_in,
                              void* d_out, int out_size, void* d_ws, size_t ws_size,
                              hipStream_t stream) {
  const float* fg = (const float*)d_in[0];
  const float* hg = (const float*)d_in[1];
  const float* qf = (const float*)d_in[2];
  const float* hq = (const float*)d_in[3];
  const float* w1 = (const float*)d_in[4];
  const float* b1 = (const float*)d_in[5];
  const float* w2 = (const float*)d_in[6];
  const float* b2 = (const float*)d_in[7];
  const float* w3 = (const float*)d_in[8];
  const float* b3 = (const float*)d_in[9];
  const float* w4 = (const float*)d_in[10];
  const float* b4 = (const float*)d_in[11];
  const float* w5 = (const float*)d_in[12];
  const float* b5 = (const float*)d_in[13];
  const float* wi = (const float*)d_in[14];
  const float* bi = (const float*)d_in[15];
  const float* wo = (const float*)d_in[16];
  const float* bo = (const float*)d_in[17];
  float* ws = (float*)d_ws;
  float* out = (float*)d_out;

  k_prep<<<4628, 256, 0, stream>>>(fg, qf, hq, w3, ws);
  k_cv<<<dim3(64, 32), 256, 0, stream>>>(qf, fg, ws);
  k_head_stripe<<<16384, 256, 0, stream>>>(w1, b1, w2, b2, b3, ws);
  k_merge_cvt<<<1984, 256, 0, stream>>>(w4, b4, w5, b5, wi, wo, ws);
  for (int it = 0; it < 4; it++) {
    k_corr<<<1024, 256, 0, stream>>>(fg, hg, ws);
    k_mix<<<64, 256, 0, stream>>>(bi, bo, ws, out);
  }
}

// Round 10
// 337.499 us; speedup vs baseline: 1.0856x; 1.0856x over previous
//
#include <hip/hip_runtime.h>
#include <hip/hip_bf16.h>
#include <math.h>

// ---------------------------------------------------------------------------
// TAPIR forward. State f32; cv + mixer GEMMs + hid3 conv via bf16 MFMA.
// fg[64,64,256] hg[128,128,128] qf[1024,256] hq[1024,128] -> out[1024,4]
// ---------------------------------------------------------------------------

#define NQ 1024
#define TEMPF 20.0f
#define DIMV 388
#define INDIM 535
#define KPAD 544
#define HID 512

// workspace layout (float offsets)
#define WS_CV      0                          // 1024*4096 (dead after stripe)
#define WS_FGAVG   (WS_CV + NQ*4096)          // 32*32*256
#define WS_POS     (WS_FGAVG + 262144)        // 1024*2
#define WS_OCC     (WS_POS + NQ*2)            // 1024
#define WS_EXPD    (WS_OCC + NQ)              // 1024
#define WS_FEATS   (WS_EXPD + NQ)             // 1024*384
#define WS_MLPIN   (WS_FEATS + NQ*384)        // bf16 mlp_in [1024][544] (278528 fl)
#define WS_HIDDEN  (WS_MLPIN + NQ*KPAD)       // bf16 hidden [1024][512] / SUM3 f32
#define WS_W3B     (WS_HIDDEN + NQ*HID)       // bf16 hid3 B-fragments (5120 bf16)
// overlays:
#define WS_PART    (WS_MLPIN + 278528)        // 1024*32*4 softmax partials
#define WS_SUM3    WS_HIDDEN                  // 1024*16*32 hid3 relu-sums (dead after merge)
#define WS_WIT     WS_CV                      // bf16 [512][544] mix_in_w^T
#define WS_WOT     (WS_CV + 139264)           // bf16 [448][512] mix_out_w^T

#define OP 72                                 // occ LDS x-pitch
#define CVP 68                                // cvs LDS pitch

typedef __attribute__((ext_vector_type(8))) short bf16x8;
typedef __attribute__((ext_vector_type(4))) float f32x4;

// ---------------------------------------------------------------------------
// prep: fg 2x2 avg pyramid, feats=concat(hq,qf), W3B fragment pack, zero SUM3
// ---------------------------------------------------------------------------
__global__ __launch_bounds__(256) void k_prep(
    const float* __restrict__ fg, const float* __restrict__ qf,
    const float* __restrict__ hq, const float* __restrict__ w3,
    float* __restrict__ ws) {
  int i = blockIdx.x * 256 + threadIdx.x;
  if (i < 262144) {
    int c = i & 255, ox = (i >> 8) & 31, oy = i >> 13;
    const float* b = fg + (((oy * 2) * 64 + ox * 2) << 8) + c;
    ws[WS_FGAVG + i] = 0.25f * (b[0] + b[256] + b[16384] + b[16384 + 256]);
  } else if (i < 262144 + 393216) {
    int j = i - 262144;
    int n = j / 384, c = j - n * 384;
    ws[WS_FEATS + j] = (c < 128) ? hq[n * 128 + c] : qf[n * 256 + c - 128];
  } else if (i < 262144 + 393216 + 5120) {
    int j = i - (262144 + 393216);
    int e = j & 7, qd = (j >> 3) & 3, nl = (j >> 5) & 15;
    int nt = (j >> 9) & 1, kt = j >> 10;
    int k = kt * 32 + qd * 8 + e;
    int ic = k & 15, tap = k >> 4;
    int oc = nt * 16 + nl;
    float v = (tap < 9) ? w3[(oc * 16 + ic) * 9 + tap] : 0.f;
    ((__hip_bfloat16*)(ws + WS_W3B))[j] = __float2bfloat16(v);
  } else if (i < 262144 + 393216 + 5120 + 524288) {
    int j = i - (262144 + 393216 + 5120);
    ws[WS_SUM3 + j] = 0.f;
  }
}

// ---------------------------------------------------------------------------
// cost volume (bf16 MFMA): cv[m=query][n=pixel] = qf . fg, K=256.
// ---------------------------------------------------------------------------
__global__ __launch_bounds__(256) void k_cv(
    const float* __restrict__ qf, const float* __restrict__ fg,
    float* __restrict__ ws) {
  __shared__ __hip_bfloat16 A_s[32 * 32];
  __shared__ __hip_bfloat16 B_s[64 * 32];
  const int t = threadIdx.x;
  const int wv = t >> 6, lane = t & 63;
  const int wm = wv & 1, wn = wv >> 1;
  const int quad = lane >> 4, nl = lane & 15;
  const int p0 = blockIdx.x * 64, m0 = blockIdx.y * 32;
  f32x4 acc0 = {0.f, 0.f, 0.f, 0.f};
  f32x4 acc1 = {0.f, 0.f, 0.f, 0.f};

  for (int k0 = 0; k0 < 256; k0 += 32) {
    {
      int r = t >> 3, c = t & 7;
      float4 v = *(const float4*)&qf[(m0 + r) * 256 + k0 + c * 4];
      union { __hip_bfloat16 h[4]; uint2 u; } pk;
      pk.h[0] = __float2bfloat16(v.x); pk.h[1] = __float2bfloat16(v.y);
      pk.h[2] = __float2bfloat16(v.z); pk.h[3] = __float2bfloat16(v.w);
      *(uint2*)&A_s[r * 32 + c * 4] = pk.u;
    }
    {
      int r = t >> 2, c = t & 3;
      const float* src = &fg[(p0 + r) * 256 + k0 + c * 8];
      float4 v0 = *(const float4*)src;
      float4 v1 = *(const float4*)(src + 4);
      union { __hip_bfloat16 h[8]; uint4 u; } pk;
      pk.h[0] = __float2bfloat16(v0.x); pk.h[1] = __float2bfloat16(v0.y);
      pk.h[2] = __float2bfloat16(v0.z); pk.h[3] = __float2bfloat16(v0.w);
      pk.h[4] = __float2bfloat16(v1.x); pk.h[5] = __float2bfloat16(v1.y);
      pk.h[6] = __float2bfloat16(v1.z); pk.h[7] = __float2bfloat16(v1.w);
      *(uint4*)&B_s[r * 32 + c * 8] = pk.u;
    }
    __syncthreads();
    bf16x8 a = *(const bf16x8*)&A_s[(16 * wm + nl) * 32 + quad * 8];
    bf16x8 b0 = *(const bf16x8*)&B_s[(32 * wn + nl) * 32 + quad * 8];
    bf16x8 b1 = *(const bf16x8*)&B_s[(32 * wn + 16 + nl) * 32 + quad * 8];
    acc0 = __builtin_amdgcn_mfma_f32_16x16x32_bf16(a, b0, acc0, 0, 0, 0);
    acc1 = __builtin_amdgcn_mfma_f32_16x16x32_bf16(a, b1, acc1, 0, 0, 0);
    __syncthreads();
  }
#pragma unroll
  for (int nt = 0; nt < 2; nt++) {
    int n = p0 + 32 * wn + nt * 16 + nl;
#pragma unroll
    for (int r = 0; r < 4; r++) {
      int m = m0 + 16 * wm + quad * 4 + r;
      ws[WS_CV + m * 4096 + n] = (nt ? acc1[r] : acc0[r]);
    }
  }
}

// ---------------------------------------------------------------------------
// head stripe kernel: 1 block = (query, 4-row stripe). 16384 blocks.
// ---------------------------------------------------------------------------
__global__ __launch_bounds__(256, 5) void k_head_stripe(
    const float* __restrict__ h1w, const float* __restrict__ h1b,
    const float* __restrict__ h2w, const float* __restrict__ h2b,
    const float* __restrict__ h3b, float* __restrict__ ws) {
  __shared__ float cvs[8 * CVP];         // cv rows y0-2..y0+5, x -1..64
  __shared__ float occ[6 * 16 * OP];     // [r][ch][x+4]

  const int bx = blockIdx.x;
  const int q = bx >> 4, st = bx & 15;
  const int y0 = st * 4;
  const int t = threadIdx.x;
  const int wv = t >> 6, lane = t & 63;
  const int role = (wv + bx) & 3;
  const float* cv = ws + WS_CV + q * 4096;

  // halo cols 0-3 / 68-71 of all 96 (r,ch) rows
  if (t < 192) {
    int rc = t >> 1, side = t & 1;
    *(float4*)&occ[rc * OP + side * 68] = make_float4(0.f, 0.f, 0.f, 0.f);
  }
  // out-of-range occ row (st==0: r=0 ; st==15: r=5)
  if (st == 0 || st == 15) {
    int r = (st == 0) ? 0 : 5;
    for (int i = t; i < 16 * 18; i += 256)
      *(float4*)&occ[(r * 16 + (i / 18)) * OP + (i % 18) * 4] =
          make_float4(0.f, 0.f, 0.f, 0.f);
  }
  // cv stripe load
#pragma unroll
  for (int j = 0; j < 2; j++) {
    int i = t + 256 * j;
    int lr = i >> 6, x = i & 63;
    int g = y0 - 2 + lr;
    cvs[lr * CVP + x + 1] = (g >= 0 && g < 64) ? cv[g * 64 + x] : 0.f;
  }
  if (t < 32) {
    int rr = t >> 2, c = t & 3;
    cvs[rr * CVP + ((c == 0) ? 0 : (64 + c))] = 0.f;  // idx 0,65,66,67
  }
  __syncthreads();

  // ---- P1: hid1 conv, 1 px/lane, wave = 4 channels (balanced) ----
  {
    const int x = lane;
    const int chg = wv * 4;
    float w1r[4][9], b1r[4];
#pragma unroll
    for (int k = 0; k < 4; k++) {
      b1r[k] = h1b[chg + k];
#pragma unroll
      for (int j = 0; j < 9; j++) w1r[k][j] = h1w[(chg + k) * 9 + j];
    }
    for (int r = 0; r < 6; r++) {
      int yo = y0 - 1 + r;
      if (yo >= 0 && yo <= 63) {
        float p[9];
#pragma unroll
        for (int ky = 0; ky < 3; ky++) {
          const float* cp = &cvs[(r + ky) * CVP + x];
          p[3 * ky] = cp[0]; p[3 * ky + 1] = cp[1]; p[3 * ky + 2] = cp[2];
        }
#pragma unroll
        for (int k = 0; k < 4; k++) {
          float a = b1r[k];
#pragma unroll
          for (int j = 0; j < 9; j++) a += w1r[k][j] * p[j];
          occ[(r * 16 + chg + k) * OP + x + 4] = fmaxf(a, 0.f);
        }
      }
    }
  }
  __syncthreads();

  if (role == 1 || role == 2) {
    // ---- hid3 MFMA: one output row (oyl = role-1). M=32 ox, N=32 oc, K=160.
    const __hip_bfloat16* W3B = (const __hip_bfloat16*)(ws + WS_W3B);
    const int oyl = role - 1;
    const int nl = lane & 15;
    const int qd = lane >> 4, qh = qd >> 1, ql = qd & 1;
    f32x4 acc00 = {0.f,0.f,0.f,0.f}, acc01 = {0.f,0.f,0.f,0.f};
    f32x4 acc10 = {0.f,0.f,0.f,0.f}, acc11 = {0.f,0.f,0.f,0.f};
#pragma unroll
    for (int kt = 0; kt < 5; kt++) {
      int tap = kt * 2 + qh;               // 0..9 (9 => zero pad)
      int tv = (tap < 9) ? tap : 0;
      int ky = (tv >= 6) ? 2 : ((tv >= 3) ? 1 : 0);
      int kx = tv - 3 * ky;
      const float* ap =
          &occ[((2 * oyl + 1 + ky) * 16 + ql * 8) * OP + 4 + kx + 2 * nl];
      union { bf16x8 v; __hip_bfloat16 h[8]; } a0u, a1u;
      if (tap < 9) {
#pragma unroll
        for (int j = 0; j < 8; j++) {
          a0u.h[j] = __float2bfloat16(ap[j * OP]);
          a1u.h[j] = __float2bfloat16(ap[j * OP + 32]);
        }
      } else {
#pragma unroll
        for (int j = 0; j < 8; j++) {
          a0u.h[j] = __float2bfloat16(0.f);
          a1u.h[j] = __float2bfloat16(0.f);
        }
      }
      bf16x8 b0 = *(const bf16x8*)&W3B[((kt * 2 + 0) * 16 + nl) * 32 + qd * 8];
      bf16x8 b1 = *(const bf16x8*)&W3B[((kt * 2 + 1) * 16 + nl) * 32 + qd * 8];
      acc00 = __builtin_amdgcn_mfma_f32_16x16x32_bf16(a0u.v, b0, acc00, 0, 0, 0);
      acc01 = __builtin_amdgcn_mfma_f32_16x16x32_bf16(a0u.v, b1, acc01, 0, 0, 0);
      acc10 = __builtin_amdgcn_mfma_f32_16x16x32_bf16(a1u.v, b0, acc10, 0, 0, 0);
      acc11 = __builtin_amdgcn_mfma_f32_16x16x32_bf16(a1u.v, b1, acc11, 0, 0, 0);
    }
    float bb0 = h3b[nl], bb1 = h3b[16 + nl];
    float s0 = 0.f, s1 = 0.f;
#pragma unroll
    for (int r = 0; r < 4; r++) {
      s0 += fmaxf(acc00[r] + bb0, 0.f) + fmaxf(acc10[r] + bb0, 0.f);
      s1 += fmaxf(acc01[r] + bb1, 0.f) + fmaxf(acc11[r] + bb1, 0.f);
    }
    s0 += __shfl_xor(s0, 16); s0 += __shfl_xor(s0, 32);
    s1 += __shfl_xor(s1, 16); s1 += __shfl_xor(s1, 32);
    if (lane < 16) {
      atomicAdd(&ws[WS_SUM3 + (q * 16 + st) * 32 + nl], s0);
      atomicAdd(&ws[WS_SUM3 + (q * 16 + st) * 32 + 16 + nl], s1);
    }
  } else {
    // ---- hid2 + softmax partial on 2 rows ----
    const int rl = ((role == 3) ? 2 : 0) + (lane >> 5);
    const int yg = y0 + rl;
    const int x0 = (lane & 31) * 2;
    float pa = 0.f, pb = 0.f;
    for (int ch = 0; ch < 16; ch++) {
#pragma unroll
      for (int ky = 0; ky < 3; ky++) {
        const float* bp = &occ[((rl + ky) * 16 + ch) * OP + x0];
        float f0 = bp[3];
        float2 fm = *(const float2*)(bp + 4);
        float f3 = bp[6];
        float wa = h2w[ch * 9 + 3 * ky], wb = h2w[ch * 9 + 3 * ky + 1],
              wc = h2w[ch * 9 + 3 * ky + 2];
        pa += wa * f0 + wb * fm.x + wc * fm.y;
        pb += wa * fm.x + wb * fm.y + wc * f3;
      }
    }
    float bb = h2b[0];
    float v0 = (pa + bb) * TEMPF, v1 = (pb + bb) * TEMPF;
    float mg = fmaxf(v0, v1);
#pragma unroll
    for (int off = 1; off < 64; off <<= 1) mg = fmaxf(mg, __shfl_xor(mg, off));
    float e0 = __expf(v0 - mg), e1 = __expf(v1 - mg);
    float s = e0 + e1;
    float sx = e0 * (float)x0 + e1 * (float)(x0 + 1);
    float sy = s * (float)yg;
#pragma unroll
    for (int off = 1; off < 64; off <<= 1) {
      s += __shfl_xor(s, off);
      sx += __shfl_xor(sx, off);
      sy += __shfl_xor(sy, off);
    }
    if (lane == 0) {
      int slot = q * 32 + st * 2 + ((role == 3) ? 1 : 0);
      *(float4*)&ws[WS_PART + slot * 4] = make_float4(mg, s, sx, sy);
    }
  }
}

// ---------------------------------------------------------------------------
// head merge (blocks 0-255) + mixer weight convert (all 1984 blocks)
// ---------------------------------------------------------------------------
__global__ __launch_bounds__(256) void k_merge_cvt(
    const float* __restrict__ w4, const float* __restrict__ b4,
    const float* __restrict__ w5, const float* __restrict__ b5,
    const float* __restrict__ wi, const float* __restrict__ wo,
    float* __restrict__ ws) {
  {
    int i = blockIdx.x * 256 + threadIdx.x;
    __hip_bfloat16* WIT = (__hip_bfloat16*)(ws + WS_WIT);
    __hip_bfloat16* WOT = (__hip_bfloat16*)(ws + WS_WOT);
    if (i < 278528) {
      int n = i / KPAD, k = i - n * KPAD;
      float v = (k < INDIM) ? wi[k * HID + n] : 0.f;
      WIT[i] = __float2bfloat16(v);
    } else if (i < 278528 + 229376) {
      int j = i - 278528;
      int n = j >> 9, k = j & 511;
      float v = (n < DIMV) ? wo[k * DIMV + n] : 0.f;
      WOT[j] = __float2bfloat16(v);
    }
  }
  if (blockIdx.x >= 256) return;

  __shared__ float sums_s[4][32];
  __shared__ float o4s[4][16];
  int t = threadIdx.x, wv = t >> 6, lane = t & 63;
  int q = blockIdx.x * 4 + wv;

  float M = -1e30f, S = 0.f, SX = 0.f, SY = 0.f;
  if (lane < 32) {
    float4 pv = *(const float4*)&ws[WS_PART + (q * 32 + lane) * 4];
    M = pv.x; S = pv.y; SX = pv.z; SY = pv.w;
  }
#pragma unroll
  for (int off = 1; off < 64; off <<= 1) {
    float Mo = __shfl_xor(M, off), So = __shfl_xor(S, off);
    float SXo = __shfl_xor(SX, off), SYo = __shfl_xor(SY, off);
    float Mn = fmaxf(M, Mo);
    float c1 = __expf(M - Mn), c2 = __expf(Mo - Mn);
    S = S * c1 + So * c2; SX = SX * c1 + SXo * c2; SY = SY * c1 + SYo * c2;
    M = Mn;
  }
  if (lane == 0) {
    ws[WS_POS + q * 2 + 0] = (SX / S) * 8.0f;
    ws[WS_POS + q * 2 + 1] = (SY / S) * 8.0f;
  }

  int ch = lane & 31, half = lane >> 5;
  float sm = 0.f;
#pragma unroll
  for (int s8 = 0; s8 < 8; s8++)
    sm += ws[WS_SUM3 + (q * 16 + half * 8 + s8) * 32 + ch];
  sm += __shfl_xor(sm, 32);
  if (lane < 32) sums_s[wv][lane] = sm * (1.f / 1024.f);
  __syncthreads();
  if (lane < 16) {
    float a = b4[lane];
#pragma unroll
    for (int i = 0; i < 32; i++) a += sums_s[wv][i] * w4[i * 16 + lane];
    o4s[wv][lane] = fmaxf(a, 0.f);
  }
  __syncthreads();
  if (lane < 2) {
    float r = b5[lane];
#pragma unroll
    for (int j = 0; j < 16; j++) r += o4s[wv][j] * w5[j * 2 + lane];
    if (lane == 0) ws[WS_OCC + q] = r;
    else           ws[WS_EXPD + q] = r;
  }
}

// ---------------------------------------------------------------------------
// correlation + bf16 mlp_in assembly. 1 block = 1 query.
// ---------------------------------------------------------------------------
__global__ __launch_bounds__(256) void k_corr(
    const float* __restrict__ fg, const float* __restrict__ hg,
    float* __restrict__ ws) {
  __shared__ float qs[384];
  __shared__ float dbuf[3][64];
  int t = threadIdx.x;
  int wv = t >> 6, lane = t & 63;
  int cl = lane & 15, sub = lane >> 4;
  int n = blockIdx.x;
  const float* feats = ws + WS_FEATS + n * 384;
  float posx = ws[WS_POS + n * 2 + 0];
  float posy = ws[WS_POS + n * 2 + 1];
  __hip_bfloat16* mi = (__hip_bfloat16*)(ws + WS_MLPIN) + n * KPAD;

  for (int col = t; col < 384; col += 256) {
    float v = feats[col];
    qs[col] = v;
    mi[4 + col] = __float2bfloat16(v);
  }
  if (t < 4) {
    float v = (t == 2) ? ws[WS_OCC + n] : ((t == 3) ? ws[WS_EXPD + n] : 0.f);
    mi[t] = __float2bfloat16(v);
  }
  __syncthreads();

  float4 qh0 = *(const float4*)&qs[cl * 4];
  float4 qh1 = *(const float4*)&qs[64 + cl * 4];
  float4 qq0 = *(const float4*)&qs[128 + cl * 4];
  float4 qq1 = *(const float4*)&qs[192 + cl * 4];
  float4 qq2 = *(const float4*)&qs[256 + cl * 4];
  float4 qq3 = *(const float4*)&qs[320 + cl * 4];

#pragma unroll
  for (int L = 0; L < 3; L++) {
    const float* grid;
    int Hg, Wg;
    float scl;
    if (L == 0)      { grid = hg;             Hg = 128; Wg = 128; scl = 0.25f; }
    else if (L == 1) { grid = fg;             Hg = 64;  Wg = 64;  scl = 0.125f; }
    else             { grid = ws + WS_FGAVG;  Hg = 32;  Wg = 32;  scl = 0.0625f; }
    float cy = posy * scl, cx = posx * scl;
    int iy = (int)floorf(cy), ix = (int)floorf(cx);
#pragma unroll
    for (int g = 0; g < 4; g++) {
      int p = wv * 16 + g * 4 + sub;
      int a = p >> 3, b = p & 7;
      int row = iy + a - 3; row = row < 0 ? 0 : (row > Hg - 1 ? Hg - 1 : row);
      int col = ix + b - 3; col = col < 0 ? 0 : (col > Wg - 1 ? Wg - 1 : col);
      float acc;
      if (L == 0) {
        const float* gp = grid + (row * Wg + col) * 128 + cl * 4;
        float4 g0 = *(const float4*)gp;
        float4 g1 = *(const float4*)(gp + 64);
        acc = g0.x * qh0.x + g0.y * qh0.y + g0.z * qh0.z + g0.w * qh0.w +
              g1.x * qh1.x + g1.y * qh1.y + g1.z * qh1.z + g1.w * qh1.w;
      } else {
        const float* gp = grid + (row * Wg + col) * 256 + cl * 4;
        float4 g0 = *(const float4*)gp;
        float4 g1 = *(const float4*)(gp + 64);
        float4 g2 = *(const float4*)(gp + 128);
        float4 g3 = *(const float4*)(gp + 192);
        acc = g0.x * qq0.x + g0.y * qq0.y + g0.z * qq0.z + g0.w * qq0.w +
              g1.x * qq1.x + g1.y * qq1.y + g1.z * qq1.z + g1.w * qq1.w +
              g2.x * qq2.x + g2.y * qq2.y + g2.z * qq2.z + g2.w * qq2.w +
              g3.x * qq3.x + g3.y * qq3.y + g3.z * qq3.z + g3.w * qq3.w;
      }
      acc += __shfl_xor(acc, 1);
      acc += __shfl_xor(acc, 2);
      acc += __shfl_xor(acc, 4);
      acc += __shfl_xor(acc, 8);
      if (cl == 0) dbuf[L][p] = acc;
    }
  }
  __syncthreads();

  if (t < 147) {
    int L = t / 49, s = t - L * 49;
    int sa = s / 7, sb = s - sa * 7;
    float scl = (L == 0) ? 0.25f : ((L == 1) ? 0.125f : 0.0625f);
    float cy = posy * scl, cx = posx * scl;
    float wy = cy - floorf(cy), wx = cx - floorf(cx);
    int i00 = sa * 8 + sb;
    float d00 = dbuf[L][i00], d01 = dbuf[L][i00 + 1];
    float d10 = dbuf[L][i00 + 8], d11 = dbuf[L][i00 + 9];
    float corr = (1.f - wy) * (1.f - wx) * d00 + (1.f - wy) * wx * d01 +
                 wy * (1.f - wx) * d10 + wy * wx * d11;
    mi[388 + t] = __float2bfloat16(corr);
  }
}

// ---------------------------------------------------------------------------
__device__ __forceinline__ float gelu_tanh(float x) {
  float z = 0.7978845608028654f * (x + 0.044715f * x * x * x);
  z = fminf(fmaxf(z, -15.f), 15.f);
  float e = __expf(2.f * z);
  float th = (e - 1.f) / (e + 1.f);
  return 0.5f * x * (1.f + th);
}

// ---------------------------------------------------------------------------
// mixer GEMM 1 (MFMA bf16): hidden = gelu(mlp_in @ mix_in_w + b)
// ---------------------------------------------------------------------------
__global__ __launch_bounds__(256) void k_mix1(
    const float* __restrict__ bias, float* __restrict__ ws) {
  __shared__ __hip_bfloat16 A_s[32 * 32];
  __shared__ __hip_bfloat16 B_s[64 * 32];
  const int t = threadIdx.x;
  const int wv = t >> 6, lane = t & 63;
  const int wm = wv & 1, wn = wv >> 1;
  const int quad = lane >> 4, nl = lane & 15;
  const int n0 = blockIdx.x * 64, m0 = blockIdx.y * 32;
  const unsigned short* Abf = (const unsigned short*)(ws + WS_MLPIN);
  const unsigned short* WIT = (const unsigned short*)(ws + WS_WIT);
  f32x4 acc0 = {0.f, 0.f, 0.f, 0.f};
  f32x4 acc1 = {0.f, 0.f, 0.f, 0.f};

  for (int k0 = 0; k0 < KPAD; k0 += 32) {
    if (t < 128) {
      int r = t >> 2, c = t & 3;
      *(uint4*)&A_s[r * 32 + c * 8] =
          *(const uint4*)&Abf[(m0 + r) * KPAD + k0 + c * 8];
    }
    {
      int r = t >> 2, c = t & 3;
      *(uint4*)&B_s[r * 32 + c * 8] =
          *(const uint4*)&WIT[(n0 + r) * KPAD + k0 + c * 8];
    }
    __syncthreads();
    bf16x8 a = *(const bf16x8*)&A_s[(16 * wm + nl) * 32 + quad * 8];
    bf16x8 b0 = *(const bf16x8*)&B_s[(32 * wn + nl) * 32 + quad * 8];
    bf16x8 b1 = *(const bf16x8*)&B_s[(32 * wn + 16 + nl) * 32 + quad * 8];
    acc0 = __builtin_amdgcn_mfma_f32_16x16x32_bf16(a, b0, acc0, 0, 0, 0);
    acc1 = __builtin_amdgcn_mfma_f32_16x16x32_bf16(a, b1, acc1, 0, 0, 0);
    __syncthreads();
  }

  __hip_bfloat16* Hd = (__hip_bfloat16*)(ws + WS_HIDDEN);
#pragma unroll
  for (int nt = 0; nt < 2; nt++) {
    int nn = n0 + 32 * wn + nt * 16 + nl;
    float bv = bias[nn];
#pragma unroll
    for (int r = 0; r < 4; r++) {
      int m = m0 + 16 * wm + quad * 4 + r;
      float v = gelu_tanh((nt ? acc1[r] : acc0[r]) + bv);
      Hd[m * HID + nn] = __float2bfloat16(v);
    }
  }
}

// ---------------------------------------------------------------------------
// mixer GEMM 2 (MFMA bf16) + state update + out write
// ---------------------------------------------------------------------------
__global__ __launch_bounds__(256) void k_mix2(
    const float* __restrict__ bias, float* __restrict__ ws,
    float* __restrict__ out) {
  __shared__ __hip_bfloat16 A_s[32 * 32];
  __shared__ __hip_bfloat16 B_s[64 * 32];
  const int t = threadIdx.x;
  const int wv = t >> 6, lane = t & 63;
  const int wm = wv & 1, wn = wv >> 1;
  const int quad = lane >> 4, nl = lane & 15;
  const int n0 = blockIdx.x * 64, m0 = blockIdx.y * 32;
  const unsigned short* Abf = (const unsigned short*)(ws + WS_HIDDEN);
  const unsigned short* WOT = (const unsigned short*)(ws + WS_WOT);
  f32x4 acc0 = {0.f, 0.f, 0.f, 0.f};
  f32x4 acc1 = {0.f, 0.f, 0.f, 0.f};

  for (int k0 = 0; k0 < HID; k0 += 32) {
    if (t < 128) {
      int r = t >> 2, c = t & 3;
      *(uint4*)&A_s[r * 32 + c * 8] =
          *(const uint4*)&Abf[(m0 + r) * HID + k0 + c * 8];
    }
    {
      int r = t >> 2, c = t & 3;
      *(uint4*)&B_s[r * 32 + c * 8] =
          *(const uint4*)&WOT[(n0 + r) * HID + k0 + c * 8];
    }
    __syncthreads();
    bf16x8 a = *(const bf16x8*)&A_s[(16 * wm + nl) * 32 + quad * 8];
    bf16x8 b0 = *(const bf16x8*)&B_s[(32 * wn + nl) * 32 + quad * 8];
    bf16x8 b1 = *(const bf16x8*)&B_s[(32 * wn + 16 + nl) * 32 + quad * 8];
    acc0 = __builtin_amdgcn_mfma_f32_16x16x32_bf16(a, b0, acc0, 0, 0, 0);
    acc1 = __builtin_amdgcn_mfma_f32_16x16x32_bf16(a, b1, acc1, 0, 0, 0);
    __syncthreads();
  }

#pragma unroll
  for (int nt = 0; nt < 2; nt++) {
    int col = n0 + 32 * wn + nt * 16 + nl;
    if (col >= DIMV) continue;
    float bv = bias[col];
#pragma unroll
    for (int r = 0; r < 4; r++) {
      int m = m0 + 16 * wm + quad * 4 + r;
      float rr = (nt ? acc1[r] : acc0[r]) + bv;
      if (col < 2) {
        float v = ws[WS_POS + m * 2 + col] + rr;
        ws[WS_POS + m * 2 + col] = v;
        out[m * 4 + col] = v;
      } else if (col == 2) {
        float v = ws[WS_OCC + m] + rr;
        ws[WS_OCC + m] = v;
        out[m * 4 + 2] = v;
      } else if (col == 3) {
        float v = ws[WS_EXPD + m] + rr;
        ws[WS_EXPD + m] = v;
        out[m * 4 + 3] = v;
      } else {
        ws[WS_FEATS + m * 384 + (col - 4)] += rr;
      }
    }
  }
}

// ---------------------------------------------------------------------------
extern "C" void kernel_launch(void* const* d_in, const int* in_sizes, int n_in,
                              void* d_out, int out_size, void* d_ws, size_t ws_size,
                              hipStream_t stream) {
  const float* fg = (const float*)d_in[0];
  const float* hg = (const float*)d_in[1];
  const float* qf = (const float*)d_in[2];
  const float* hq = (const float*)d_in[3];
  const float* w1 = (const float*)d_in[4];
  const float* b1 = (const float*)d_in[5];
  const float* w2 = (const float*)d_in[6];
  const float* b2 = (const float*)d_in[7];
  const float* w3 = (const float*)d_in[8];
  const float* b3 = (const float*)d_in[9];
  const float* w4 = (const float*)d_in[10];
  const float* b4 = (const float*)d_in[11];
  const float* w5 = (const float*)d_in[12];
  const float* b5 = (const float*)d_in[13];
  const float* wi = (const float*)d_in[14];
  const float* bi = (const float*)d_in[15];
  const float* wo = (const float*)d_in[16];
  const float* bo = (const float*)d_in[17];
  float* ws = (float*)d_ws;
  float* out = (float*)d_out;

  k_prep<<<4628, 256, 0, stream>>>(fg, qf, hq, w3, ws);
  k_cv<<<dim3(64, 32), 256, 0, stream>>>(qf, fg, ws);
  k_head_stripe<<<16384, 256, 0, stream>>>(w1, b1, w2, b2, b3, ws);
  k_merge_cvt<<<1984, 256, 0, stream>>>(w4, b4, w5, b5, wi, wo, ws);
  for (int it = 0; it < 4; it++) {
    k_corr<<<1024, 256, 0, stream>>>(fg, hg, ws);
    k_mix1<<<dim3(8, 32), 256, 0, stream>>>(bi, ws);
    k_mix2<<<dim3(7, 32), 256, 0, stream>>>(bo, ws, out);
  }
}

// Round 11
// 310.484 us; speedup vs baseline: 1.1800x; 1.0870x over previous
//
#include <hip/hip_runtime.h>
#include <hip/hip_bf16.h>
#include <math.h>

// ---------------------------------------------------------------------------
// TAPIR forward. State f32; cv + mixer GEMMs + hid3 conv via bf16 MFMA.
// fg[64,64,256] hg[128,128,128] qf[1024,256] hq[1024,128] -> out[1024,4]
// ---------------------------------------------------------------------------

#define NQ 1024
#define TEMPF 20.0f
#define DIMV 388
#define INDIM 535
#define KPAD 544
#define HID 512

// workspace layout (float offsets)
#define WS_CV      0                          // 1024*4096 (dead after stripe)
#define WS_FGAVG   (WS_CV + NQ*4096)          // 32*32*256
#define WS_POS     (WS_FGAVG + 262144)        // 1024*2
#define WS_OCC     (WS_POS + NQ*2)            // 1024
#define WS_EXPD    (WS_OCC + NQ)              // 1024
#define WS_FEATS   (WS_EXPD + NQ)             // 1024*384
#define WS_MLPIN   (WS_FEATS + NQ*384)        // bf16 mlp_in [1024][544] (278528 fl)
#define WS_HIDDEN  (WS_MLPIN + NQ*KPAD)       // bf16 hidden [1024][512] / SUM3 f32
#define WS_W3B     (WS_HIDDEN + NQ*HID)       // bf16 hid3 B-fragments (5120 bf16)
// overlays:
#define WS_PART    (WS_MLPIN + 278528)        // 1024*32*4 softmax partials
#define WS_SUM3    WS_HIDDEN                  // 1024*16*32 hid3 relu-sums (dead after merge)
#define WS_WIT     WS_CV                      // bf16 [512][544] mix_in_w^T
#define WS_WOT     (WS_CV + 139264)           // bf16 [448][512] mix_out_w^T

#define OP 72                                 // occ LDS x-pitch
#define CVP 68                                // cvs LDS pitch

typedef __attribute__((ext_vector_type(8))) short bf16x8;
typedef __attribute__((ext_vector_type(4))) float f32x4;

// ---------------------------------------------------------------------------
// fused prep + cost volume.
// blocks 0..2047: cv (bf16 MFMA) 32m x 64n tiles.
// blocks 2048..6675: prep (fgavg, feats, W3B pack, SUM3 zero).
// ---------------------------------------------------------------------------
__global__ __launch_bounds__(256) void k_prep_cv(
    const float* __restrict__ fg, const float* __restrict__ qf,
    const float* __restrict__ hq, const float* __restrict__ w3,
    float* __restrict__ ws) {
  __shared__ __hip_bfloat16 A_s[32 * 32];
  __shared__ __hip_bfloat16 B_s[64 * 32];
  const int bx = blockIdx.x;
  const int t = threadIdx.x;

  if (bx >= 2048) {
    // ---- prep part ----
    int i = (bx - 2048) * 256 + t;
    if (i < 262144) {
      int c = i & 255, ox = (i >> 8) & 31, oy = i >> 13;
      const float* b = fg + (((oy * 2) * 64 + ox * 2) << 8) + c;
      ws[WS_FGAVG + i] = 0.25f * (b[0] + b[256] + b[16384] + b[16384 + 256]);
    } else if (i < 262144 + 393216) {
      int j = i - 262144;
      int n = j / 384, c = j - n * 384;
      ws[WS_FEATS + j] = (c < 128) ? hq[n * 128 + c] : qf[n * 256 + c - 128];
    } else if (i < 262144 + 393216 + 5120) {
      int j = i - (262144 + 393216);
      int e = j & 7, qd = (j >> 3) & 3, nl = (j >> 5) & 15;
      int nt = (j >> 9) & 1, kt = j >> 10;
      int k = kt * 32 + qd * 8 + e;
      int ic = k & 15, tap = k >> 4;
      int oc = nt * 16 + nl;
      float v = (tap < 9) ? w3[(oc * 16 + ic) * 9 + tap] : 0.f;
      ((__hip_bfloat16*)(ws + WS_W3B))[j] = __float2bfloat16(v);
    } else if (i < 262144 + 393216 + 5120 + 524288) {
      int j = i - (262144 + 393216 + 5120);
      ws[WS_SUM3 + j] = 0.f;
    }
    return;
  }

  // ---- cv part ----
  const int wv = t >> 6, lane = t & 63;
  const int wm = wv & 1, wn = wv >> 1;
  const int quad = lane >> 4, nl = lane & 15;
  const int p0 = (bx & 63) * 64, m0 = (bx >> 6) * 32;
  f32x4 acc0 = {0.f, 0.f, 0.f, 0.f};
  f32x4 acc1 = {0.f, 0.f, 0.f, 0.f};

  for (int k0 = 0; k0 < 256; k0 += 32) {
    {
      int r = t >> 3, c = t & 7;
      float4 v = *(const float4*)&qf[(m0 + r) * 256 + k0 + c * 4];
      union { __hip_bfloat16 h[4]; uint2 u; } pk;
      pk.h[0] = __float2bfloat16(v.x); pk.h[1] = __float2bfloat16(v.y);
      pk.h[2] = __float2bfloat16(v.z); pk.h[3] = __float2bfloat16(v.w);
      *(uint2*)&A_s[r * 32 + c * 4] = pk.u;
    }
    {
      int r = t >> 2, c = t & 3;
      const float* src = &fg[(p0 + r) * 256 + k0 + c * 8];
      float4 v0 = *(const float4*)src;
      float4 v1 = *(const float4*)(src + 4);
      union { __hip_bfloat16 h[8]; uint4 u; } pk;
      pk.h[0] = __float2bfloat16(v0.x); pk.h[1] = __float2bfloat16(v0.y);
      pk.h[2] = __float2bfloat16(v0.z); pk.h[3] = __float2bfloat16(v0.w);
      pk.h[4] = __float2bfloat16(v1.x); pk.h[5] = __float2bfloat16(v1.y);
      pk.h[6] = __float2bfloat16(v1.z); pk.h[7] = __float2bfloat16(v1.w);
      *(uint4*)&B_s[r * 32 + c * 8] = pk.u;
    }
    __syncthreads();
    bf16x8 a = *(const bf16x8*)&A_s[(16 * wm + nl) * 32 + quad * 8];
    bf16x8 b0 = *(const bf16x8*)&B_s[(32 * wn + nl) * 32 + quad * 8];
    bf16x8 b1 = *(const bf16x8*)&B_s[(32 * wn + 16 + nl) * 32 + quad * 8];
    acc0 = __builtin_amdgcn_mfma_f32_16x16x32_bf16(a, b0, acc0, 0, 0, 0);
    acc1 = __builtin_amdgcn_mfma_f32_16x16x32_bf16(a, b1, acc1, 0, 0, 0);
    __syncthreads();
  }
#pragma unroll
  for (int nt = 0; nt < 2; nt++) {
    int n = p0 + 32 * wn + nt * 16 + nl;
#pragma unroll
    for (int r = 0; r < 4; r++) {
      int m = m0 + 16 * wm + quad * 4 + r;
      ws[WS_CV + m * 4096 + n] = (nt ? acc1[r] : acc0[r]);
    }
  }
}

// ---------------------------------------------------------------------------
// head stripe kernel: 1 block = (query, 4-row stripe). 16384 blocks.
// ---------------------------------------------------------------------------
__global__ __launch_bounds__(256, 5) void k_head_stripe(
    const float* __restrict__ h1w, const float* __restrict__ h1b,
    const float* __restrict__ h2w, const float* __restrict__ h2b,
    const float* __restrict__ h3b, float* __restrict__ ws) {
  __shared__ float cvs[8 * CVP];         // cv rows y0-2..y0+5, x -1..64
  __shared__ float occ[6 * 16 * OP];     // [r][ch][x+4]

  const int bx = blockIdx.x;
  const int q = bx >> 4, st = bx & 15;
  const int y0 = st * 4;
  const int t = threadIdx.x;
  const int wv = t >> 6, lane = t & 63;
  const int role = (wv + bx) & 3;
  const float* cv = ws + WS_CV + q * 4096;

  // halo cols 0-3 / 68-71 of all 96 (r,ch) rows
  if (t < 192) {
    int rc = t >> 1, side = t & 1;
    *(float4*)&occ[rc * OP + side * 68] = make_float4(0.f, 0.f, 0.f, 0.f);
  }
  // out-of-range occ row (st==0: r=0 ; st==15: r=5)
  if (st == 0 || st == 15) {
    int r = (st == 0) ? 0 : 5;
    for (int i = t; i < 16 * 18; i += 256)
      *(float4*)&occ[(r * 16 + (i / 18)) * OP + (i % 18) * 4] =
          make_float4(0.f, 0.f, 0.f, 0.f);
  }
  // cv stripe load
#pragma unroll
  for (int j = 0; j < 2; j++) {
    int i = t + 256 * j;
    int lr = i >> 6, x = i & 63;
    int g = y0 - 2 + lr;
    cvs[lr * CVP + x + 1] = (g >= 0 && g < 64) ? cv[g * 64 + x] : 0.f;
  }
  if (t < 32) {
    int rr = t >> 2, c = t & 3;
    cvs[rr * CVP + ((c == 0) ? 0 : (64 + c))] = 0.f;  // idx 0,65,66,67
  }
  __syncthreads();

  // ---- P1: hid1 conv, 1 px/lane, wave = 4 channels ----
  {
    const int x = lane;
    const int chg = wv * 4;
    float w1r[4][9], b1r[4];
#pragma unroll
    for (int k = 0; k < 4; k++) {
      b1r[k] = h1b[chg + k];
#pragma unroll
      for (int j = 0; j < 9; j++) w1r[k][j] = h1w[(chg + k) * 9 + j];
    }
    for (int r = 0; r < 6; r++) {
      int yo = y0 - 1 + r;
      if (yo >= 0 && yo <= 63) {
        float p[9];
#pragma unroll
        for (int ky = 0; ky < 3; ky++) {
          const float* cp = &cvs[(r + ky) * CVP + x];
          p[3 * ky] = cp[0]; p[3 * ky + 1] = cp[1]; p[3 * ky + 2] = cp[2];
        }
#pragma unroll
        for (int k = 0; k < 4; k++) {
          float a = b1r[k];
#pragma unroll
          for (int j = 0; j < 9; j++) a += w1r[k][j] * p[j];
          occ[(r * 16 + chg + k) * OP + x + 4] = fmaxf(a, 0.f);
        }
      }
    }
  }
  __syncthreads();

  if (role == 1 || role == 2) {
    // ---- hid3 MFMA: one output row (oyl = role-1). M=32 ox, N=32 oc, K=160.
    const __hip_bfloat16* W3B = (const __hip_bfloat16*)(ws + WS_W3B);
    const int oyl = role - 1;
    const int nl = lane & 15;
    const int qd = lane >> 4, qh = qd >> 1, ql = qd & 1;
    f32x4 acc00 = {0.f,0.f,0.f,0.f}, acc01 = {0.f,0.f,0.f,0.f};
    f32x4 acc10 = {0.f,0.f,0.f,0.f}, acc11 = {0.f,0.f,0.f,0.f};
#pragma unroll
    for (int kt = 0; kt < 5; kt++) {
      int tap = kt * 2 + qh;               // 0..9 (9 => zero pad)
      int tv = (tap < 9) ? tap : 0;
      int ky = (tv >= 6) ? 2 : ((tv >= 3) ? 1 : 0);
      int kx = tv - 3 * ky;
      const float* ap =
          &occ[((2 * oyl + 1 + ky) * 16 + ql * 8) * OP + 4 + kx + 2 * nl];
      union { bf16x8 v; __hip_bfloat16 h[8]; } a0u, a1u;
      if (tap < 9) {
#pragma unroll
        for (int j = 0; j < 8; j++) {
          a0u.h[j] = __float2bfloat16(ap[j * OP]);
          a1u.h[j] = __float2bfloat16(ap[j * OP + 32]);
        }
      } else {
#pragma unroll
        for (int j = 0; j < 8; j++) {
          a0u.h[j] = __float2bfloat16(0.f);
          a1u.h[j] = __float2bfloat16(0.f);
        }
      }
      bf16x8 b0 = *(const bf16x8*)&W3B[((kt * 2 + 0) * 16 + nl) * 32 + qd * 8];
      bf16x8 b1 = *(const bf16x8*)&W3B[((kt * 2 + 1) * 16 + nl) * 32 + qd * 8];
      acc00 = __builtin_amdgcn_mfma_f32_16x16x32_bf16(a0u.v, b0, acc00, 0, 0, 0);
      acc01 = __builtin_amdgcn_mfma_f32_16x16x32_bf16(a0u.v, b1, acc01, 0, 0, 0);
      acc10 = __builtin_amdgcn_mfma_f32_16x16x32_bf16(a1u.v, b0, acc10, 0, 0, 0);
      acc11 = __builtin_amdgcn_mfma_f32_16x16x32_bf16(a1u.v, b1, acc11, 0, 0, 0);
    }
    float bb0 = h3b[nl], bb1 = h3b[16 + nl];
    float s0 = 0.f, s1 = 0.f;
#pragma unroll
    for (int r = 0; r < 4; r++) {
      s0 += fmaxf(acc00[r] + bb0, 0.f) + fmaxf(acc10[r] + bb0, 0.f);
      s1 += fmaxf(acc01[r] + bb1, 0.f) + fmaxf(acc11[r] + bb1, 0.f);
    }
    s0 += __shfl_xor(s0, 16); s0 += __shfl_xor(s0, 32);
    s1 += __shfl_xor(s1, 16); s1 += __shfl_xor(s1, 32);
    if (lane < 16) {
      atomicAdd(&ws[WS_SUM3 + (q * 16 + st) * 32 + nl], s0);
      atomicAdd(&ws[WS_SUM3 + (q * 16 + st) * 32 + 16 + nl], s1);
    }
  } else {
    // ---- hid2 + softmax partial on 2 rows ----
    const int rl = ((role == 3) ? 2 : 0) + (lane >> 5);
    const int yg = y0 + rl;
    const int x0 = (lane & 31) * 2;
    float pa = 0.f, pb = 0.f;
    for (int ch = 0; ch < 16; ch++) {
#pragma unroll
      for (int ky = 0; ky < 3; ky++) {
        const float* bp = &occ[((rl + ky) * 16 + ch) * OP + x0];
        float f0 = bp[3];
        float2 fm = *(const float2*)(bp + 4);
        float f3 = bp[6];
        float wa = h2w[ch * 9 + 3 * ky], wb = h2w[ch * 9 + 3 * ky + 1],
              wc = h2w[ch * 9 + 3 * ky + 2];
        pa += wa * f0 + wb * fm.x + wc * fm.y;
        pb += wa * fm.x + wb * fm.y + wc * f3;
      }
    }
    float bb = h2b[0];
    float v0 = (pa + bb) * TEMPF, v1 = (pb + bb) * TEMPF;
    float mg = fmaxf(v0, v1);
#pragma unroll
    for (int off = 1; off < 64; off <<= 1) mg = fmaxf(mg, __shfl_xor(mg, off));
    float e0 = __expf(v0 - mg), e1 = __expf(v1 - mg);
    float s = e0 + e1;
    float sx = e0 * (float)x0 + e1 * (float)(x0 + 1);
    float sy = s * (float)yg;
#pragma unroll
    for (int off = 1; off < 64; off <<= 1) {
      s += __shfl_xor(s, off);
      sx += __shfl_xor(sx, off);
      sy += __shfl_xor(sy, off);
    }
    if (lane == 0) {
      int slot = q * 32 + st * 2 + ((role == 3) ? 1 : 0);
      *(float4*)&ws[WS_PART + slot * 4] = make_float4(mg, s, sx, sy);
    }
  }
}

// ---------------------------------------------------------------------------
// head merge (blocks 0-255) + mixer weight convert (all 1984 blocks)
// ---------------------------------------------------------------------------
__global__ __launch_bounds__(256) void k_merge_cvt(
    const float* __restrict__ w4, const float* __restrict__ b4,
    const float* __restrict__ w5, const float* __restrict__ b5,
    const float* __restrict__ wi, const float* __restrict__ wo,
    float* __restrict__ ws) {
  {
    int i = blockIdx.x * 256 + threadIdx.x;
    __hip_bfloat16* WIT = (__hip_bfloat16*)(ws + WS_WIT);
    __hip_bfloat16* WOT = (__hip_bfloat16*)(ws + WS_WOT);
    if (i < 278528) {
      int n = i / KPAD, k = i - n * KPAD;
      float v = (k < INDIM) ? wi[k * HID + n] : 0.f;
      WIT[i] = __float2bfloat16(v);
    } else if (i < 278528 + 229376) {
      int j = i - 278528;
      int n = j >> 9, k = j & 511;
      float v = (n < DIMV) ? wo[k * DIMV + n] : 0.f;
      WOT[j] = __float2bfloat16(v);
    }
  }
  if (blockIdx.x >= 256) return;

  __shared__ float sums_s[4][32];
  __shared__ float o4s[4][16];
  int t = threadIdx.x, wv = t >> 6, lane = t & 63;
  int q = blockIdx.x * 4 + wv;

  float M = -1e30f, S = 0.f, SX = 0.f, SY = 0.f;
  if (lane < 32) {
    float4 pv = *(const float4*)&ws[WS_PART + (q * 32 + lane) * 4];
    M = pv.x; S = pv.y; SX = pv.z; SY = pv.w;
  }
#pragma unroll
  for (int off = 1; off < 64; off <<= 1) {
    float Mo = __shfl_xor(M, off), So = __shfl_xor(S, off);
    float SXo = __shfl_xor(SX, off), SYo = __shfl_xor(SY, off);
    float Mn = fmaxf(M, Mo);
    float c1 = __expf(M - Mn), c2 = __expf(Mo - Mn);
    S = S * c1 + So * c2; SX = SX * c1 + SXo * c2; SY = SY * c1 + SYo * c2;
    M = Mn;
  }
  if (lane == 0) {
    ws[WS_POS + q * 2 + 0] = (SX / S) * 8.0f;
    ws[WS_POS + q * 2 + 1] = (SY / S) * 8.0f;
  }

  int ch = lane & 31, half = lane >> 5;
  float sm = 0.f;
#pragma unroll
  for (int s8 = 0; s8 < 8; s8++)
    sm += ws[WS_SUM3 + (q * 16 + half * 8 + s8) * 32 + ch];
  sm += __shfl_xor(sm, 32);
  if (lane < 32) sums_s[wv][lane] = sm * (1.f / 1024.f);
  __syncthreads();
  if (lane < 16) {
    float a = b4[lane];
#pragma unroll
    for (int i = 0; i < 32; i++) a += sums_s[wv][i] * w4[i * 16 + lane];
    o4s[wv][lane] = fmaxf(a, 0.f);
  }
  __syncthreads();
  if (lane < 2) {
    float r = b5[lane];
#pragma unroll
    for (int j = 0; j < 16; j++) r += o4s[wv][j] * w5[j * 2 + lane];
    if (lane == 0) ws[WS_OCC + q] = r;
    else           ws[WS_EXPD + q] = r;
  }
}

// ---------------------------------------------------------------------------
// correlation + bf16 mlp_in assembly. 1 block = 1 query.
// ---------------------------------------------------------------------------
__global__ __launch_bounds__(256) void k_corr(
    const float* __restrict__ fg, const float* __restrict__ hg,
    float* __restrict__ ws) {
  __shared__ float qs[384];
  __shared__ float dbuf[3][64];
  int t = threadIdx.x;
  int wv = t >> 6, lane = t & 63;
  int cl = lane & 15, sub = lane >> 4;
  int n = blockIdx.x;
  const float* feats = ws + WS_FEATS + n * 384;
  float posx = ws[WS_POS + n * 2 + 0];
  float posy = ws[WS_POS + n * 2 + 1];
  __hip_bfloat16* mi = (__hip_bfloat16*)(ws + WS_MLPIN) + n * KPAD;

  for (int col = t; col < 384; col += 256) {
    float v = feats[col];
    qs[col] = v;
    mi[4 + col] = __float2bfloat16(v);
  }
  if (t < 4) {
    float v = (t == 2) ? ws[WS_OCC + n] : ((t == 3) ? ws[WS_EXPD + n] : 0.f);
    mi[t] = __float2bfloat16(v);
  }
  __syncthreads();

  float4 qh0 = *(const float4*)&qs[cl * 4];
  float4 qh1 = *(const float4*)&qs[64 + cl * 4];
  float4 qq0 = *(const float4*)&qs[128 + cl * 4];
  float4 qq1 = *(const float4*)&qs[192 + cl * 4];
  float4 qq2 = *(const float4*)&qs[256 + cl * 4];
  float4 qq3 = *(const float4*)&qs[320 + cl * 4];

#pragma unroll
  for (int L = 0; L < 3; L++) {
    const float* grid;
    int Hg, Wg;
    float scl;
    if (L == 0)      { grid = hg;             Hg = 128; Wg = 128; scl = 0.25f; }
    else if (L == 1) { grid = fg;             Hg = 64;  Wg = 64;  scl = 0.125f; }
    else             { grid = ws + WS_FGAVG;  Hg = 32;  Wg = 32;  scl = 0.0625f; }
    float cy = posy * scl, cx = posx * scl;
    int iy = (int)floorf(cy), ix = (int)floorf(cx);
#pragma unroll
    for (int g = 0; g < 4; g++) {
      int p = wv * 16 + g * 4 + sub;
      int a = p >> 3, b = p & 7;
      int row = iy + a - 3; row = row < 0 ? 0 : (row > Hg - 1 ? Hg - 1 : row);
      int col = ix + b - 3; col = col < 0 ? 0 : (col > Wg - 1 ? Wg - 1 : col);
      float acc;
      if (L == 0) {
        const float* gp = grid + (row * Wg + col) * 128 + cl * 4;
        float4 g0 = *(const float4*)gp;
        float4 g1 = *(const float4*)(gp + 64);
        acc = g0.x * qh0.x + g0.y * qh0.y + g0.z * qh0.z + g0.w * qh0.w +
              g1.x * qh1.x + g1.y * qh1.y + g1.z * qh1.z + g1.w * qh1.w;
      } else {
        const float* gp = grid + (row * Wg + col) * 256 + cl * 4;
        float4 g0 = *(const float4*)gp;
        float4 g1 = *(const float4*)(gp + 64);
        float4 g2 = *(const float4*)(gp + 128);
        float4 g3 = *(const float4*)(gp + 192);
        acc = g0.x * qq0.x + g0.y * qq0.y + g0.z * qq0.z + g0.w * qq0.w +
              g1.x * qq1.x + g1.y * qq1.y + g1.z * qq1.z + g1.w * qq1.w +
              g2.x * qq2.x + g2.y * qq2.y + g2.z * qq2.z + g2.w * qq2.w +
              g3.x * qq3.x + g3.y * qq3.y + g3.z * qq3.z + g3.w * qq3.w;
      }
      acc += __shfl_xor(acc, 1);
      acc += __shfl_xor(acc, 2);
      acc += __shfl_xor(acc, 4);
      acc += __shfl_xor(acc, 8);
      if (cl == 0) dbuf[L][p] = acc;
    }
  }
  __syncthreads();

  if (t < 147) {
    int L = t / 49, s = t - L * 49;
    int sa = s / 7, sb = s - sa * 7;
    float scl = (L == 0) ? 0.25f : ((L == 1) ? 0.125f : 0.0625f);
    float cy = posy * scl, cx = posx * scl;
    float wy = cy - floorf(cy), wx = cx - floorf(cx);
    int i00 = sa * 8 + sb;
    float d00 = dbuf[L][i00], d01 = dbuf[L][i00 + 1];
    float d10 = dbuf[L][i00 + 8], d11 = dbuf[L][i00 + 9];
    float corr = (1.f - wy) * (1.f - wx) * d00 + (1.f - wy) * wx * d01 +
                 wy * (1.f - wx) * d10 + wy * wx * d11;
    mi[388 + t] = __float2bfloat16(corr);
  }
}

// ---------------------------------------------------------------------------
__device__ __forceinline__ float gelu_tanh(float x) {
  float z = 0.7978845608028654f * (x + 0.044715f * x * x * x);
  z = fminf(fmaxf(z, -15.f), 15.f);
  float e = __expf(2.f * z);
  float th = (e - 1.f) / (e + 1.f);
  return 0.5f * x * (1.f + th);
}

// ---------------------------------------------------------------------------
// mixer GEMM 1 (MFMA bf16): hidden = gelu(mlp_in @ mix_in_w + b)
// 32x32 tile, wave = 16x16 quadrant. grid (16, 32) = 512 blocks.
// ---------------------------------------------------------------------------
__global__ __launch_bounds__(256) void k_mix1(
    const float* __restrict__ bias, float* __restrict__ ws) {
  __shared__ __hip_bfloat16 A_s[32 * 32];
  __shared__ __hip_bfloat16 B_s[32 * 32];
  const int t = threadIdx.x;
  const int wv = t >> 6, lane = t & 63;
  const int wm = wv & 1, wn = wv >> 1;
  const int quad = lane >> 4, nl = lane & 15;
  const int n0 = blockIdx.x * 32, m0 = blockIdx.y * 32;
  const unsigned short* Abf = (const unsigned short*)(ws + WS_MLPIN);
  const unsigned short* WIT = (const unsigned short*)(ws + WS_WIT);
  f32x4 acc = {0.f, 0.f, 0.f, 0.f};

  for (int k0 = 0; k0 < KPAD; k0 += 32) {
    if (t < 128) {
      int r = t >> 2, c = t & 3;
      *(uint4*)&A_s[r * 32 + c * 8] =
          *(const uint4*)&Abf[(m0 + r) * KPAD + k0 + c * 8];
    } else {
      int tt = t - 128;
      int r = tt >> 2, c = tt & 3;
      *(uint4*)&B_s[r * 32 + c * 8] =
          *(const uint4*)&WIT[(n0 + r) * KPAD + k0 + c * 8];
    }
    __syncthreads();
    bf16x8 a = *(const bf16x8*)&A_s[(16 * wm + nl) * 32 + quad * 8];
    bf16x8 b = *(const bf16x8*)&B_s[(16 * wn + nl) * 32 + quad * 8];
    acc = __builtin_amdgcn_mfma_f32_16x16x32_bf16(a, b, acc, 0, 0, 0);
    __syncthreads();
  }

  __hip_bfloat16* Hd = (__hip_bfloat16*)(ws + WS_HIDDEN);
  int nn = n0 + 16 * wn + nl;
  float bv = bias[nn];
#pragma unroll
  for (int r = 0; r < 4; r++) {
    int m = m0 + 16 * wm + quad * 4 + r;
    Hd[m * HID + nn] = __float2bfloat16(gelu_tanh(acc[r] + bv));
  }
}

// ---------------------------------------------------------------------------
// mixer GEMM 2 (MFMA bf16) + state update + out write
// 32x32 tile, wave = 16x16 quadrant. grid (13, 32) = 416 blocks.
// ---------------------------------------------------------------------------
__global__ __launch_bounds__(256) void k_mix2(
    const float* __restrict__ bias, float* __restrict__ ws,
    float* __restrict__ out) {
  __shared__ __hip_bfloat16 A_s[32 * 32];
  __shared__ __hip_bfloat16 B_s[32 * 32];
  const int t = threadIdx.x;
  const int wv = t >> 6, lane = t & 63;
  const int wm = wv & 1, wn = wv >> 1;
  const int quad = lane >> 4, nl = lane & 15;
  const int n0 = blockIdx.x * 32, m0 = blockIdx.y * 32;
  const unsigned short* Abf = (const unsigned short*)(ws + WS_HIDDEN);
  const unsigned short* WOT = (const unsigned short*)(ws + WS_WOT);
  f32x4 acc = {0.f, 0.f, 0.f, 0.f};

  for (int k0 = 0; k0 < HID; k0 += 32) {
    if (t < 128) {
      int r = t >> 2, c = t & 3;
      *(uint4*)&A_s[r * 32 + c * 8] =
          *(const uint4*)&Abf[(m0 + r) * HID + k0 + c * 8];
    } else {
      int tt = t - 128;
      int r = tt >> 2, c = tt & 3;
      *(uint4*)&B_s[r * 32 + c * 8] =
          *(const uint4*)&WOT[(n0 + r) * HID + k0 + c * 8];
    }
    __syncthreads();
    bf16x8 a = *(const bf16x8*)&A_s[(16 * wm + nl) * 32 + quad * 8];
    bf16x8 b = *(const bf16x8*)&B_s[(16 * wn + nl) * 32 + quad * 8];
    acc = __builtin_amdgcn_mfma_f32_16x16x32_bf16(a, b, acc, 0, 0, 0);
    __syncthreads();
  }

  int col = n0 + 16 * wn + nl;
  if (col < DIMV) {
    float bv = bias[col];
#pragma unroll
    for (int r = 0; r < 4; r++) {
      int m = m0 + 16 * wm + quad * 4 + r;
      float rr = acc[r] + bv;
      if (col < 2) {
        float v = ws[WS_POS + m * 2 + col] + rr;
        ws[WS_POS + m * 2 + col] = v;
        out[m * 4 + col] = v;
      } else if (col == 2) {
        float v = ws[WS_OCC + m] + rr;
        ws[WS_OCC + m] = v;
        out[m * 4 + 2] = v;
      } else if (col == 3) {
        float v = ws[WS_EXPD + m] + rr;
        ws[WS_EXPD + m] = v;
        out[m * 4 + 3] = v;
      } else {
        ws[WS_FEATS + m * 384 + (col - 4)] += rr;
      }
    }
  }
}

// ---------------------------------------------------------------------------
extern "C" void kernel_launch(void* const* d_in, const int* in_sizes, int n_in,
                              void* d_out, int out_size, void* d_ws, size_t ws_size,
                              hipStream_t stream) {
  const float* fg = (const float*)d_in[0];
  const float* hg = (const float*)d_in[1];
  const float* qf = (const float*)d_in[2];
  const float* hq = (const float*)d_in[3];
  const float* w1 = (const float*)d_in[4];
  const float* b1 = (const float*)d_in[5];
  const float* w2 = (const float*)d_in[6];
  const float* b2 = (const float*)d_in[7];
  const float* w3 = (const float*)d_in[8];
  const float* b3 = (const float*)d_in[9];
  const float* w4 = (const float*)d_in[10];
  const float* b4 = (const float*)d_in[11];
  const float* w5 = (const float*)d_in[12];
  const float* b5 = (const float*)d_in[13];
  const float* wi = (const float*)d_in[14];
  const float* bi = (const float*)d_in[15];
  const float* wo = (const float*)d_in[16];
  const float* bo = (const float*)d_in[17];
  float* ws = (float*)d_ws;
  float* out = (float*)d_out;

  k_prep_cv<<<6676, 256, 0, stream>>>(fg, qf, hq, w3, ws);
  k_head_stripe<<<16384, 256, 0, stream>>>(w1, b1, w2, b2, b3, ws);
  k_merge_cvt<<<1984, 256, 0, stream>>>(w4, b4, w5, b5, wi, wo, ws);
  for (int it = 0; it < 4; it++) {
    k_corr<<<1024, 256, 0, stream>>>(fg, hg, ws);
    k_mix1<<<dim3(16, 32), 256, 0, stream>>>(bi, ws);
    k_mix2<<<dim3(13, 32), 256, 0, stream>>>(bo, ws, out);
  }
}

// Round 12
// 309.247 us; speedup vs baseline: 1.1847x; 1.0040x over previous
//
#include <hip/hip_runtime.h>
#include <hip/hip_bf16.h>
#include <math.h>

// ---------------------------------------------------------------------------
// TAPIR forward. State f32; cv + mixer GEMMs + hid3 conv via bf16 MFMA.
// fg[64,64,256] hg[128,128,128] qf[1024,256] hq[1024,128] -> out[1024,4]
// ---------------------------------------------------------------------------

#define NQ 1024
#define TEMPF 20.0f
#define DIMV 388
#define INDIM 535
#define KPAD 544
#define HID 512

// workspace layout (float offsets). Old WS_CV region [0, 4194304) reused:
//   [0, 2097152)        bf16 cv [1024][4096]            (dead after stripe)
//   [2097152, ...)      WIT / WOT / bf16 grids          (written after stripe)
#define WS_CVB     0
#define WS_WIT     2097152                    // bf16 [512][544]
#define WS_WOT     2236416                    // bf16 [448][512]
#define WS_FG16    2351104                    // bf16 fg copy (1048576)
#define WS_HG16    2875392                    // bf16 hg copy (2097152)
#define WS_AV16    3923968                    // bf16 fgavg copy (262144)
#define WS_FGAVG   4194304                    // f32 32*32*256
#define WS_POS     (WS_FGAVG + 262144)        // 1024*2
#define WS_OCC     (WS_POS + NQ*2)            // 1024
#define WS_EXPD    (WS_OCC + NQ)              // 1024
#define WS_FEATS   (WS_EXPD + NQ)             // 1024*384
#define WS_MLPIN   (WS_FEATS + NQ*384)        // bf16 mlp_in [1024][544]
#define WS_HIDDEN  (WS_MLPIN + NQ*KPAD)       // bf16 hidden [1024][512] / SUM3
#define WS_W3B     (WS_HIDDEN + NQ*HID)       // bf16 hid3 B-fragments
#define WS_PART    (WS_MLPIN + 278528)        // softmax partials overlay
#define WS_SUM3    WS_HIDDEN                  // hid3 relu-sums overlay

#define OP 72                                 // occ LDS x-pitch
#define CVP 68                                // cvs LDS pitch

typedef __attribute__((ext_vector_type(8))) short bf16x8;
typedef __attribute__((ext_vector_type(4))) float f32x4;

union BU8 { uint4 u; __hip_bfloat16 h[8]; };

// ---------------------------------------------------------------------------
// fused prep + cost volume.
// blocks 0..2047: cv (bf16 MFMA) -> bf16 store.
// blocks 2048..: prep (fgavg, feats + bf16 mlp_in init, W3B pack, SUM3 zero).
// ---------------------------------------------------------------------------
__global__ __launch_bounds__(256) void k_prep_cv(
    const float* __restrict__ fg, const float* __restrict__ qf,
    const float* __restrict__ hq, const float* __restrict__ w3,
    float* __restrict__ ws) {
  __shared__ __hip_bfloat16 A_s[32 * 32];
  __shared__ __hip_bfloat16 B_s[64 * 32];
  const int bx = blockIdx.x;
  const int t = threadIdx.x;

  if (bx >= 2048) {
    int i = (bx - 2048) * 256 + t;
    if (i < 262144) {
      int c = i & 255, ox = (i >> 8) & 31, oy = i >> 13;
      const float* b = fg + (((oy * 2) * 64 + ox * 2) << 8) + c;
      ws[WS_FGAVG + i] = 0.25f * (b[0] + b[256] + b[16384] + b[16384 + 256]);
    } else if (i < 262144 + 393216) {
      int j = i - 262144;
      int n = j / 384, c = j - n * 384;
      float v = (c < 128) ? hq[n * 128 + c] : qf[n * 256 + c - 128];
      ws[WS_FEATS + j] = v;
      __hip_bfloat16* mi = (__hip_bfloat16*)(ws + WS_MLPIN);
      mi[n * KPAD + 4 + c] = __float2bfloat16(v);
      if (c == 0) {
        mi[n * KPAD + 0] = __float2bfloat16(0.f);
        mi[n * KPAD + 1] = __float2bfloat16(0.f);
      }
    } else if (i < 262144 + 393216 + 5120) {
      int j = i - (262144 + 393216);
      int e = j & 7, qd = (j >> 3) & 3, nl = (j >> 5) & 15;
      int nt = (j >> 9) & 1, kt = j >> 10;
      int k = kt * 32 + qd * 8 + e;
      int ic = k & 15, tap = k >> 4;
      int oc = nt * 16 + nl;
      float v = (tap < 9) ? w3[(oc * 16 + ic) * 9 + tap] : 0.f;
      ((__hip_bfloat16*)(ws + WS_W3B))[j] = __float2bfloat16(v);
    } else if (i < 262144 + 393216 + 5120 + 524288) {
      int j = i - (262144 + 393216 + 5120);
      ws[WS_SUM3 + j] = 0.f;
    }
    return;
  }

  // ---- cv part ----
  const int wv = t >> 6, lane = t & 63;
  const int wm = wv & 1, wn = wv >> 1;
  const int quad = lane >> 4, nl = lane & 15;
  const int p0 = (bx & 63) * 64, m0 = (bx >> 6) * 32;
  f32x4 acc0 = {0.f, 0.f, 0.f, 0.f};
  f32x4 acc1 = {0.f, 0.f, 0.f, 0.f};

  for (int k0 = 0; k0 < 256; k0 += 32) {
    {
      int r = t >> 3, c = t & 7;
      float4 v = *(const float4*)&qf[(m0 + r) * 256 + k0 + c * 4];
      union { __hip_bfloat16 h[4]; uint2 u; } pk;
      pk.h[0] = __float2bfloat16(v.x); pk.h[1] = __float2bfloat16(v.y);
      pk.h[2] = __float2bfloat16(v.z); pk.h[3] = __float2bfloat16(v.w);
      *(uint2*)&A_s[r * 32 + c * 4] = pk.u;
    }
    {
      int r = t >> 2, c = t & 3;
      const float* src = &fg[(p0 + r) * 256 + k0 + c * 8];
      float4 v0 = *(const float4*)src;
      float4 v1 = *(const float4*)(src + 4);
      union { __hip_bfloat16 h[8]; uint4 u; } pk;
      pk.h[0] = __float2bfloat16(v0.x); pk.h[1] = __float2bfloat16(v0.y);
      pk.h[2] = __float2bfloat16(v0.z); pk.h[3] = __float2bfloat16(v0.w);
      pk.h[4] = __float2bfloat16(v1.x); pk.h[5] = __float2bfloat16(v1.y);
      pk.h[6] = __float2bfloat16(v1.z); pk.h[7] = __float2bfloat16(v1.w);
      *(uint4*)&B_s[r * 32 + c * 8] = pk.u;
    }
    __syncthreads();
    bf16x8 a = *(const bf16x8*)&A_s[(16 * wm + nl) * 32 + quad * 8];
    bf16x8 b0 = *(const bf16x8*)&B_s[(32 * wn + nl) * 32 + quad * 8];
    bf16x8 b1 = *(const bf16x8*)&B_s[(32 * wn + 16 + nl) * 32 + quad * 8];
    acc0 = __builtin_amdgcn_mfma_f32_16x16x32_bf16(a, b0, acc0, 0, 0, 0);
    acc1 = __builtin_amdgcn_mfma_f32_16x16x32_bf16(a, b1, acc1, 0, 0, 0);
    __syncthreads();
  }
  __hip_bfloat16* cvb = (__hip_bfloat16*)ws;
#pragma unroll
  for (int nt = 0; nt < 2; nt++) {
    int n = p0 + 32 * wn + nt * 16 + nl;
#pragma unroll
    for (int r = 0; r < 4; r++) {
      int m = m0 + 16 * wm + quad * 4 + r;
      cvb[m * 4096 + n] = __float2bfloat16(nt ? acc1[r] : acc0[r]);
    }
  }
}

// ---------------------------------------------------------------------------
// head stripe kernel: 1 block = (query, 4-row stripe). 16384 blocks.
// ---------------------------------------------------------------------------
__global__ __launch_bounds__(256, 5) void k_head_stripe(
    const float* __restrict__ h1w, const float* __restrict__ h1b,
    const float* __restrict__ h2w, const float* __restrict__ h2b,
    const float* __restrict__ h3b, float* __restrict__ ws) {
  __shared__ float cvs[8 * CVP];         // cv rows y0-2..y0+5, x -1..64
  __shared__ float occ[6 * 16 * OP];     // [r][ch][x+4]

  const int bx = blockIdx.x;
  const int q = bx >> 4, st = bx & 15;
  const int y0 = st * 4;
  const int t = threadIdx.x;
  const int wv = t >> 6, lane = t & 63;
  const int role = (wv + bx) & 3;
  const __hip_bfloat16* cvb = (const __hip_bfloat16*)ws + q * 4096;

  // halo cols 0-3 / 68-71 of all 96 (r,ch) rows
  if (t < 192) {
    int rc = t >> 1, side = t & 1;
    *(float4*)&occ[rc * OP + side * 68] = make_float4(0.f, 0.f, 0.f, 0.f);
  }
  // out-of-range occ row (st==0: r=0 ; st==15: r=5)
  if (st == 0 || st == 15) {
    int r = (st == 0) ? 0 : 5;
    for (int i = t; i < 16 * 18; i += 256)
      *(float4*)&occ[(r * 16 + (i / 18)) * OP + (i % 18) * 4] =
          make_float4(0.f, 0.f, 0.f, 0.f);
  }
  // cv stripe load (bf16 -> f32)
#pragma unroll
  for (int j = 0; j < 2; j++) {
    int i = t + 256 * j;
    int lr = i >> 6, x = i & 63;
    int g = y0 - 2 + lr;
    cvs[lr * CVP + x + 1] =
        (g >= 0 && g < 64) ? __bfloat162float(cvb[g * 64 + x]) : 0.f;
  }
  if (t < 32) {
    int rr = t >> 2, c = t & 3;
    cvs[rr * CVP + ((c == 0) ? 0 : (64 + c))] = 0.f;  // idx 0,65,66,67
  }
  __syncthreads();

  // ---- P1: hid1 conv, 1 px/lane, rolling 3x3 window, wave = 4 channels ----
  {
    const int x = lane;
    const int chg = wv * 4;
    float w1r[4][9], b1r[4];
#pragma unroll
    for (int k = 0; k < 4; k++) {
      b1r[k] = h1b[chg + k];
#pragma unroll
      for (int j = 0; j < 9; j++) w1r[k][j] = h1w[(chg + k) * 9 + j];
    }
    float win[3][3];
#pragma unroll
    for (int j = 0; j < 3; j++) {
      const float* cp = &cvs[j * CVP + x];
      win[j][0] = cp[0]; win[j][1] = cp[1]; win[j][2] = cp[2];
    }
    for (int r = 0; r < 6; r++) {
      if (r > 0) {
#pragma unroll
        for (int c = 0; c < 3; c++) { win[0][c] = win[1][c]; win[1][c] = win[2][c]; }
        const float* cp = &cvs[(r + 2) * CVP + x];
        win[2][0] = cp[0]; win[2][1] = cp[1]; win[2][2] = cp[2];
      }
      int yo = y0 - 1 + r;
      if (yo >= 0 && yo <= 63) {
#pragma unroll
        for (int k = 0; k < 4; k++) {
          float a = b1r[k];
#pragma unroll
          for (int ky = 0; ky < 3; ky++)
            a += w1r[k][3 * ky] * win[ky][0] + w1r[k][3 * ky + 1] * win[ky][1] +
                 w1r[k][3 * ky + 2] * win[ky][2];
          occ[(r * 16 + chg + k) * OP + x + 4] = fmaxf(a, 0.f);
        }
      }
    }
  }
  __syncthreads();

  if (role == 1 || role == 2) {
    // ---- hid3 MFMA: one output row (oyl = role-1). M=32 ox, N=32 oc, K=160.
    const __hip_bfloat16* W3B = (const __hip_bfloat16*)(ws + WS_W3B);
    const int oyl = role - 1;
    const int nl = lane & 15;
    const int qd = lane >> 4, qh = qd >> 1, ql = qd & 1;
    f32x4 acc00 = {0.f,0.f,0.f,0.f}, acc01 = {0.f,0.f,0.f,0.f};
    f32x4 acc10 = {0.f,0.f,0.f,0.f}, acc11 = {0.f,0.f,0.f,0.f};
#pragma unroll
    for (int kt = 0; kt < 5; kt++) {
      int tap = kt * 2 + qh;               // 0..9 (9 => zero pad)
      int tv = (tap < 9) ? tap : 0;
      int ky = (tv >= 6) ? 2 : ((tv >= 3) ? 1 : 0);
      int kx = tv - 3 * ky;
      const float* ap =
          &occ[((2 * oyl + 1 + ky) * 16 + ql * 8) * OP + 4 + kx + 2 * nl];
      union { bf16x8 v; __hip_bfloat16 h[8]; } a0u, a1u;
      if (tap < 9) {
#pragma unroll
        for (int j = 0; j < 8; j++) {
          a0u.h[j] = __float2bfloat16(ap[j * OP]);
          a1u.h[j] = __float2bfloat16(ap[j * OP + 32]);
        }
      } else {
#pragma unroll
        for (int j = 0; j < 8; j++) {
          a0u.h[j] = __float2bfloat16(0.f);
          a1u.h[j] = __float2bfloat16(0.f);
        }
      }
      bf16x8 b0 = *(const bf16x8*)&W3B[((kt * 2 + 0) * 16 + nl) * 32 + qd * 8];
      bf16x8 b1 = *(const bf16x8*)&W3B[((kt * 2 + 1) * 16 + nl) * 32 + qd * 8];
      acc00 = __builtin_amdgcn_mfma_f32_16x16x32_bf16(a0u.v, b0, acc00, 0, 0, 0);
      acc01 = __builtin_amdgcn_mfma_f32_16x16x32_bf16(a0u.v, b1, acc01, 0, 0, 0);
      acc10 = __builtin_amdgcn_mfma_f32_16x16x32_bf16(a1u.v, b0, acc10, 0, 0, 0);
      acc11 = __builtin_amdgcn_mfma_f32_16x16x32_bf16(a1u.v, b1, acc11, 0, 0, 0);
    }
    float bb0 = h3b[nl], bb1 = h3b[16 + nl];
    float s0 = 0.f, s1 = 0.f;
#pragma unroll
    for (int r = 0; r < 4; r++) {
      s0 += fmaxf(acc00[r] + bb0, 0.f) + fmaxf(acc10[r] + bb0, 0.f);
      s1 += fmaxf(acc01[r] + bb1, 0.f) + fmaxf(acc11[r] + bb1, 0.f);
    }
    s0 += __shfl_xor(s0, 16); s0 += __shfl_xor(s0, 32);
    s1 += __shfl_xor(s1, 16); s1 += __shfl_xor(s1, 32);
    if (lane < 16) {
      atomicAdd(&ws[WS_SUM3 + (q * 16 + st) * 32 + nl], s0);
      atomicAdd(&ws[WS_SUM3 + (q * 16 + st) * 32 + 16 + nl], s1);
    }
  } else {
    // ---- hid2 + softmax partial on 2 rows ----
    const int rl = ((role == 3) ? 2 : 0) + (lane >> 5);
    const int yg = y0 + rl;
    const int x0 = (lane & 31) * 2;
    float pa = 0.f, pb = 0.f;
    for (int ch = 0; ch < 16; ch++) {
#pragma unroll
      for (int ky = 0; ky < 3; ky++) {
        const float* bp = &occ[((rl + ky) * 16 + ch) * OP + x0];
        float f0 = bp[3];
        float2 fm = *(const float2*)(bp + 4);
        float f3 = bp[6];
        float wa = h2w[ch * 9 + 3 * ky], wb = h2w[ch * 9 + 3 * ky + 1],
              wc = h2w[ch * 9 + 3 * ky + 2];
        pa += wa * f0 + wb * fm.x + wc * fm.y;
        pb += wa * fm.x + wb * fm.y + wc * f3;
      }
    }
    float bb = h2b[0];
    float v0 = (pa + bb) * TEMPF, v1 = (pb + bb) * TEMPF;
    float mg = fmaxf(v0, v1);
#pragma unroll
    for (int off = 1; off < 64; off <<= 1) mg = fmaxf(mg, __shfl_xor(mg, off));
    float e0 = __expf(v0 - mg), e1 = __expf(v1 - mg);
    float s = e0 + e1;
    float sx = e0 * (float)x0 + e1 * (float)(x0 + 1);
    float sy = s * (float)yg;
#pragma unroll
    for (int off = 1; off < 64; off <<= 1) {
      s += __shfl_xor(s, off);
      sx += __shfl_xor(sx, off);
      sy += __shfl_xor(sy, off);
    }
    if (lane == 0) {
      int slot = q * 32 + st * 2 + ((role == 3) ? 1 : 0);
      *(float4*)&ws[WS_PART + slot * 4] = make_float4(mg, s, sx, sy);
    }
  }
}

// ---------------------------------------------------------------------------
// head merge (blocks 0-255) + weight/grid bf16 convert (all blocks)
// ---------------------------------------------------------------------------
__global__ __launch_bounds__(256) void k_merge_cvt(
    const float* __restrict__ w4, const float* __restrict__ b4,
    const float* __restrict__ w5, const float* __restrict__ b5,
    const float* __restrict__ wi, const float* __restrict__ wo,
    const float* __restrict__ fg, const float* __restrict__ hg,
    float* __restrict__ ws) {
  {
    int i = blockIdx.x * 256 + threadIdx.x;
    __hip_bfloat16* WIT = (__hip_bfloat16*)(ws + WS_WIT);
    __hip_bfloat16* WOT = (__hip_bfloat16*)(ws + WS_WOT);
    if (i < 278528) {
      int n = i / KPAD, k = i - n * KPAD;
      float v = (k < INDIM) ? wi[k * HID + n] : 0.f;
      WIT[i] = __float2bfloat16(v);
    } else if (i < 507904) {
      int j = i - 278528;
      int n = j >> 9, k = j & 511;
      float v = (n < DIMV) ? wo[k * DIMV + n] : 0.f;
      WOT[j] = __float2bfloat16(v);
    } else {
      int j = i - 507904;
      if (j < 1048576) {
        ((__hip_bfloat16*)(ws + WS_FG16))[j] = __float2bfloat16(fg[j]);
      } else if (j < 3145728) {
        int k = j - 1048576;
        ((__hip_bfloat16*)(ws + WS_HG16))[k] = __float2bfloat16(hg[k]);
      } else if (j < 3407872) {
        int k = j - 3145728;
        ((__hip_bfloat16*)(ws + WS_AV16))[k] = __float2bfloat16(ws[WS_FGAVG + k]);
      }
    }
  }
  if (blockIdx.x >= 256) return;

  __shared__ float sums_s[4][32];
  __shared__ float o4s[4][16];
  int t = threadIdx.x, wv = t >> 6, lane = t & 63;
  int q = blockIdx.x * 4 + wv;

  float M = -1e30f, S = 0.f, SX = 0.f, SY = 0.f;
  if (lane < 32) {
    float4 pv = *(const float4*)&ws[WS_PART + (q * 32 + lane) * 4];
    M = pv.x; S = pv.y; SX = pv.z; SY = pv.w;
  }
#pragma unroll
  for (int off = 1; off < 64; off <<= 1) {
    float Mo = __shfl_xor(M, off), So = __shfl_xor(S, off);
    float SXo = __shfl_xor(SX, off), SYo = __shfl_xor(SY, off);
    float Mn = fmaxf(M, Mo);
    float c1 = __expf(M - Mn), c2 = __expf(Mo - Mn);
    S = S * c1 + So * c2; SX = SX * c1 + SXo * c2; SY = SY * c1 + SYo * c2;
    M = Mn;
  }
  if (lane == 0) {
    ws[WS_POS + q * 2 + 0] = (SX / S) * 8.0f;
    ws[WS_POS + q * 2 + 1] = (SY / S) * 8.0f;
  }

  int ch = lane & 31, half = lane >> 5;
  float sm = 0.f;
#pragma unroll
  for (int s8 = 0; s8 < 8; s8++)
    sm += ws[WS_SUM3 + (q * 16 + half * 8 + s8) * 32 + ch];
  sm += __shfl_xor(sm, 32);
  if (lane < 32) sums_s[wv][lane] = sm * (1.f / 1024.f);
  __syncthreads();
  if (lane < 16) {
    float a = b4[lane];
#pragma unroll
    for (int i = 0; i < 32; i++) a += sums_s[wv][i] * w4[i * 16 + lane];
    o4s[wv][lane] = fmaxf(a, 0.f);
  }
  __syncthreads();
  if (lane < 2) {
    float r = b5[lane];
#pragma unroll
    for (int j = 0; j < 16; j++) r += o4s[wv][j] * w5[j * 2 + lane];
    __hip_bfloat16* mi = (__hip_bfloat16*)(ws + WS_MLPIN);
    if (lane == 0) { ws[WS_OCC + q] = r;  mi[q * KPAD + 2] = __float2bfloat16(r); }
    else           { ws[WS_EXPD + q] = r; mi[q * KPAD + 3] = __float2bfloat16(r); }
  }
}

// ---------------------------------------------------------------------------
// correlation (bf16 grids). 1 block = 1 query; writes only corr cols.
// ---------------------------------------------------------------------------
__global__ __launch_bounds__(256) void k_corr(float* __restrict__ ws) {
  __shared__ float qs[384];
  __shared__ float dbuf[3][64];
  int t = threadIdx.x;
  int wv = t >> 6, lane = t & 63;
  int cl = lane & 15, sub = lane >> 4;
  int n = blockIdx.x;
  const float* feats = ws + WS_FEATS + n * 384;
  float posx = ws[WS_POS + n * 2 + 0];
  float posy = ws[WS_POS + n * 2 + 1];
  __hip_bfloat16* mi = (__hip_bfloat16*)(ws + WS_MLPIN) + n * KPAD;

  for (int col = t; col < 384; col += 256) qs[col] = feats[col];
  __syncthreads();

  // q fragments: L0 -> 8 ch/lane from qs[0..128); L1/L2 -> 16 ch/lane from +128
  float qh[8], qq[16];
#pragma unroll
  for (int j = 0; j < 8; j++) qh[j] = qs[cl * 8 + j];
#pragma unroll
  for (int j = 0; j < 16; j++) qq[j] = qs[128 + cl * 16 + j];

  const __hip_bfloat16* G0 = (const __hip_bfloat16*)(ws + WS_HG16);
  const __hip_bfloat16* G1 = (const __hip_bfloat16*)(ws + WS_FG16);
  const __hip_bfloat16* G2 = (const __hip_bfloat16*)(ws + WS_AV16);

#pragma unroll
  for (int L = 0; L < 3; L++) {
    const __hip_bfloat16* grid;
    int Hg, Wg;
    float scl;
    if (L == 0)      { grid = G0; Hg = 128; Wg = 128; scl = 0.25f; }
    else if (L == 1) { grid = G1; Hg = 64;  Wg = 64;  scl = 0.125f; }
    else             { grid = G2; Hg = 32;  Wg = 32;  scl = 0.0625f; }
    float cy = posy * scl, cx = posx * scl;
    int iy = (int)floorf(cy), ix = (int)floorf(cx);
#pragma unroll
    for (int g = 0; g < 4; g++) {
      int p = wv * 16 + g * 4 + sub;
      int a = p >> 3, b = p & 7;
      int row = iy + a - 3; row = row < 0 ? 0 : (row > Hg - 1 ? Hg - 1 : row);
      int col = ix + b - 3; col = col < 0 ? 0 : (col > Wg - 1 ? Wg - 1 : col);
      float acc = 0.f;
      if (L == 0) {
        BU8 g0; g0.u = *(const uint4*)(grid + (row * Wg + col) * 128 + cl * 8);
#pragma unroll
        for (int j = 0; j < 8; j++) acc += __bfloat162float(g0.h[j]) * qh[j];
      } else {
        const __hip_bfloat16* gp = grid + (row * Wg + col) * 256 + cl * 16;
        BU8 g0, g1;
        g0.u = *(const uint4*)gp;
        g1.u = *(const uint4*)(gp + 8);
#pragma unroll
        for (int j = 0; j < 8; j++) {
          acc += __bfloat162float(g0.h[j]) * qq[j];
          acc += __bfloat162float(g1.h[j]) * qq[8 + j];
        }
      }
      acc += __shfl_xor(acc, 1);
      acc += __shfl_xor(acc, 2);
      acc += __shfl_xor(acc, 4);
      acc += __shfl_xor(acc, 8);
      if (cl == 0) dbuf[L][p] = acc;
    }
  }
  __syncthreads();

  if (t < 147) {
    int L = t / 49, s = t - L * 49;
    int sa = s / 7, sb = s - sa * 7;
    float scl = (L == 0) ? 0.25f : ((L == 1) ? 0.125f : 0.0625f);
    float cy = posy * scl, cx = posx * scl;
    float wy = cy - floorf(cy), wx = cx - floorf(cx);
    int i00 = sa * 8 + sb;
    float d00 = dbuf[L][i00], d01 = dbuf[L][i00 + 1];
    float d10 = dbuf[L][i00 + 8], d11 = dbuf[L][i00 + 9];
    float corr = (1.f - wy) * (1.f - wx) * d00 + (1.f - wy) * wx * d01 +
                 wy * (1.f - wx) * d10 + wy * wx * d11;
    mi[388 + t] = __float2bfloat16(corr);
  }
}

// ---------------------------------------------------------------------------
__device__ __forceinline__ float gelu_tanh(float x) {
  float z = 0.7978845608028654f * (x + 0.044715f * x * x * x);
  z = fminf(fmaxf(z, -15.f), 15.f);
  float e = __expf(2.f * z);
  float th = (e - 1.f) / (e + 1.f);
  return 0.5f * x * (1.f + th);
}

// ---------------------------------------------------------------------------
// mixer GEMM 1 (MFMA bf16): hidden = gelu(mlp_in @ mix_in_w + b). 32x32 tile.
// ---------------------------------------------------------------------------
__global__ __launch_bounds__(256) void k_mix1(
    const float* __restrict__ bias, float* __restrict__ ws) {
  __shared__ __hip_bfloat16 A_s[32 * 32];
  __shared__ __hip_bfloat16 B_s[32 * 32];
  const int t = threadIdx.x;
  const int wv = t >> 6, lane = t & 63;
  const int wm = wv & 1, wn = wv >> 1;
  const int quad = lane >> 4, nl = lane & 15;
  const int n0 = blockIdx.x * 32, m0 = blockIdx.y * 32;
  const unsigned short* Abf = (const unsigned short*)(ws + WS_MLPIN);
  const unsigned short* WIT = (const unsigned short*)(ws + WS_WIT);
  f32x4 acc = {0.f, 0.f, 0.f, 0.f};

  for (int k0 = 0; k0 < KPAD; k0 += 32) {
    if (t < 128) {
      int r = t >> 2, c = t & 3;
      *(uint4*)&A_s[r * 32 + c * 8] =
          *(const uint4*)&Abf[(m0 + r) * KPAD + k0 + c * 8];
    } else {
      int tt = t - 128;
      int r = tt >> 2, c = tt & 3;
      *(uint4*)&B_s[r * 32 + c * 8] =
          *(const uint4*)&WIT[(n0 + r) * KPAD + k0 + c * 8];
    }
    __syncthreads();
    bf16x8 a = *(const bf16x8*)&A_s[(16 * wm + nl) * 32 + quad * 8];
    bf16x8 b = *(const bf16x8*)&B_s[(16 * wn + nl) * 32 + quad * 8];
    acc = __builtin_amdgcn_mfma_f32_16x16x32_bf16(a, b, acc, 0, 0, 0);
    __syncthreads();
  }

  __hip_bfloat16* Hd = (__hip_bfloat16*)(ws + WS_HIDDEN);
  int nn = n0 + 16 * wn + nl;
  float bv = bias[nn];
#pragma unroll
  for (int r = 0; r < 4; r++) {
    int m = m0 + 16 * wm + quad * 4 + r;
    Hd[m * HID + nn] = __float2bfloat16(gelu_tanh(acc[r] + bv));
  }
}

// ---------------------------------------------------------------------------
// mixer GEMM 2 (MFMA bf16) + state update (f32 + bf16 mlp_in) + out write
// ---------------------------------------------------------------------------
__global__ __launch_bounds__(256) void k_mix2(
    const float* __restrict__ bias, float* __restrict__ ws,
    float* __restrict__ out) {
  __shared__ __hip_bfloat16 A_s[32 * 32];
  __shared__ __hip_bfloat16 B_s[32 * 32];
  const int t = threadIdx.x;
  const int wv = t >> 6, lane = t & 63;
  const int wm = wv & 1, wn = wv >> 1;
  const int quad = lane >> 4, nl = lane & 15;
  const int n0 = blockIdx.x * 32, m0 = blockIdx.y * 32;
  const unsigned short* Abf = (const unsigned short*)(ws + WS_HIDDEN);
  const unsigned short* WOT = (const unsigned short*)(ws + WS_WOT);
  f32x4 acc = {0.f, 0.f, 0.f, 0.f};

  for (int k0 = 0; k0 < HID; k0 += 32) {
    if (t < 128) {
      int r = t >> 2, c = t & 3;
      *(uint4*)&A_s[r * 32 + c * 8] =
          *(const uint4*)&Abf[(m0 + r) * HID + k0 + c * 8];
    } else {
      int tt = t - 128;
      int r = tt >> 2, c = tt & 3;
      *(uint4*)&B_s[r * 32 + c * 8] =
          *(const uint4*)&WOT[(n0 + r) * HID + k0 + c * 8];
    }
    __syncthreads();
    bf16x8 a = *(const bf16x8*)&A_s[(16 * wm + nl) * 32 + quad * 8];
    bf16x8 b = *(const bf16x8*)&B_s[(16 * wn + nl) * 32 + quad * 8];
    acc = __builtin_amdgcn_mfma_f32_16x16x32_bf16(a, b, acc, 0, 0, 0);
    __syncthreads();
  }

  int col = n0 + 16 * wn + nl;
  if (col < DIMV) {
    float bv = bias[col];
    __hip_bfloat16* mib = (__hip_bfloat16*)(ws + WS_MLPIN);
#pragma unroll
    for (int r = 0; r < 4; r++) {
      int m = m0 + 16 * wm + quad * 4 + r;
      float rr = acc[r] + bv;
      if (col < 2) {
        float v = ws[WS_POS + m * 2 + col] + rr;
        ws[WS_POS + m * 2 + col] = v;
        out[m * 4 + col] = v;
      } else if (col == 2) {
        float v = ws[WS_OCC + m] + rr;
        ws[WS_OCC + m] = v;
        out[m * 4 + 2] = v;
        mib[m * KPAD + 2] = __float2bfloat16(v);
      } else if (col == 3) {
        float v = ws[WS_EXPD + m] + rr;
        ws[WS_EXPD + m] = v;
        out[m * 4 + 3] = v;
        mib[m * KPAD + 3] = __float2bfloat16(v);
      } else {
        float v = ws[WS_FEATS + m * 384 + (col - 4)] + rr;
        ws[WS_FEATS + m * 384 + (col - 4)] = v;
        mib[m * KPAD + col] = __float2bfloat16(v);
      }
    }
  }
}

// ---------------------------------------------------------------------------
extern "C" void kernel_launch(void* const* d_in, const int* in_sizes, int n_in,
                              void* d_out, int out_size, void* d_ws, size_t ws_size,
                              hipStream_t stream) {
  const float* fg = (const float*)d_in[0];
  const float* hg = (const float*)d_in[1];
  const float* qf = (const float*)d_in[2];
  const float* hq = (const float*)d_in[3];
  const float* w1 = (const float*)d_in[4];
  const float* b1 = (const float*)d_in[5];
  const float* w2 = (const float*)d_in[6];
  const float* b2 = (const float*)d_in[7];
  const float* w3 = (const float*)d_in[8];
  const float* b3 = (const float*)d_in[9];
  const float* w4 = (const float*)d_in[10];
  const float* b4 = (const float*)d_in[11];
  const float* w5 = (const float*)d_in[12];
  const float* b5 = (const float*)d_in[13];
  const float* wi = (const float*)d_in[14];
  const float* bi = (const float*)d_in[15];
  const float* wo = (const float*)d_in[16];
  const float* bo = (const float*)d_in[17];
  float* ws = (float*)d_ws;
  float* out = (float*)d_out;

  k_prep_cv<<<6676, 256, 0, stream>>>(fg, qf, hq, w3, ws);
  k_head_stripe<<<16384, 256, 0, stream>>>(w1, b1, w2, b2, b3, ws);
  k_merge_cvt<<<15296, 256, 0, stream>>>(w4, b4, w5, b5, wi, wo, fg, hg, ws);
  for (int it = 0; it < 4; it++) {
    k_corr<<<1024, 256, 0, stream>>>(ws);
    k_mix1<<<dim3(16, 32), 256, 0, stream>>>(bi, ws);
    k_mix2<<<dim3(13, 32), 256, 0, stream>>>(bo, ws, out);
  }
}